// Round 2
// baseline (2367.078 us; speedup 1.0000x reference)
//
#include <hip/hip_runtime.h>
#include <hip/hip_bf16.h>
#include <math.h>

#define B_   2
#define S_   2048
#define HID_ 2048
#define H_   16
#define HK_  4
#define D_   128
#define NH_  24          // H + 2*HK
#define QKVN 3072        // NH_ * D_
#define R_   64

// ---------------------------------------------------------------------------
// SGEMM: C[M][N] = A[M][K] * B[N][K]^T   (both A and B are K-contiguous)
// 128x128 tile, BK=8, 256 threads, 8x8 accumulators per thread.
// ---------------------------------------------------------------------------
__global__ __launch_bounds__(256) void sgemm_bt(
    const float* __restrict__ A, const float* __restrict__ Bm,
    float* __restrict__ C, int M, int N, int K)
{
    __shared__ float As[8][132];   // [k][m], +4 pad keeps float4 alignment
    __shared__ float Bs[8][132];   // [k][n]

    const int tid = threadIdx.x;
    const int tx = tid & 15, ty = tid >> 4;
    const int m0 = blockIdx.y * 128, n0 = blockIdx.x * 128;

    const int lrow = tid >> 1;        // 0..127
    const int lk   = (tid & 1) * 4;   // 0 or 4

    const float* Ap = A  + (size_t)(m0 + lrow) * K + lk;
    const float* Bp = Bm + (size_t)(n0 + lrow) * K + lk;

    float acc[8][8];
#pragma unroll
    for (int i = 0; i < 8; ++i)
#pragma unroll
        for (int j = 0; j < 8; ++j) acc[i][j] = 0.f;

    for (int k0 = 0; k0 < K; k0 += 8) {
        float4 av = *(const float4*)(Ap + k0);
        float4 bv = *(const float4*)(Bp + k0);
        __syncthreads();
        As[lk+0][lrow] = av.x; As[lk+1][lrow] = av.y;
        As[lk+2][lrow] = av.z; As[lk+3][lrow] = av.w;
        Bs[lk+0][lrow] = bv.x; Bs[lk+1][lrow] = bv.y;
        Bs[lk+2][lrow] = bv.z; Bs[lk+3][lrow] = bv.w;
        __syncthreads();
#pragma unroll
        for (int kk = 0; kk < 8; ++kk) {
            float a[8], b[8];
            *(float4*)&a[0] = *(const float4*)&As[kk][ty*8];
            *(float4*)&a[4] = *(const float4*)&As[kk][ty*8+4];
            *(float4*)&b[0] = *(const float4*)&Bs[kk][tx*8];
            *(float4*)&b[4] = *(const float4*)&Bs[kk][tx*8+4];
#pragma unroll
            for (int i = 0; i < 8; ++i)
#pragma unroll
                for (int j = 0; j < 8; ++j)
                    acc[i][j] = fmaf(a[i], b[j], acc[i][j]);
        }
    }

#pragma unroll
    for (int i = 0; i < 8; ++i) {
        float* Cp = C + (size_t)(m0 + ty*8 + i) * N + n0 + tx*8;
        *(float4*)Cp       = *(float4*)&acc[i][0];
        *(float4*)(Cp + 4) = *(float4*)&acc[i][4];
    }
}

// ---------------------------------------------------------------------------
// Fused RMSNorm (q,k heads) + partial RoPE (first 64 dims) + QKV split.
// qkv: (B*S, 24, 128) -> Q:(B,H,S,D)  K:(B,HK,S,D)  V:(B,HK,S,D)
// One 128-thread block per (head, token).
// ---------------------------------------------------------------------------
__global__ __launch_bounds__(128) void norm_rope(
    const float* __restrict__ qkv,
    const float* __restrict__ cosT, const float* __restrict__ sinT,
    const float* __restrict__ qw, const float* __restrict__ kw,
    float* __restrict__ Q, float* __restrict__ Ko, float* __restrict__ Vo)
{
    const int h = blockIdx.x;       // 0..23
    const int s = blockIdx.y;       // 0..2047
    const int b = blockIdx.z;       // 0..1
    const int d = threadIdx.x;      // 0..127
    const size_t tok = (size_t)b * S_ + s;

    float x = qkv[(tok * NH_ + h) * D_ + d];
    __shared__ float sh[128];
    float y = x;

    if (h < 20) {   // q or k head: rmsnorm + rope
        sh[d] = x * x;
        __syncthreads();
#pragma unroll
        for (int off = 64; off >= 1; off >>= 1) {
            if (d < off) sh[d] += sh[d + off];
            __syncthreads();
        }
        float var = sh[0] * (1.f / 128.f);
        float scale = rsqrtf(var + 1e-6f);
        const float* w = (h < 16) ? qw : kw;
        y = x * scale * w[d];
        __syncthreads();
        sh[d] = y;
        __syncthreads();
        if (d < R_) {
            float c  = cosT[tok * R_ + d];
            float sn = sinT[tok * R_ + d];
            float other = (d < 32) ? -sh[d + 32] : sh[d - 32];
            y = y * c + other * sn;
        }
    }

    if (h < 16)
        Q[(((size_t)b * H_ + h) * S_ + s) * D_ + d] = y;
    else if (h < 20)
        Ko[(((size_t)b * HK_ + (h - 16)) * S_ + s) * D_ + d] = y;
    else
        Vo[(((size_t)b * HK_ + (h - 20)) * S_ + s) * D_ + d] = y;
}

// ---------------------------------------------------------------------------
// Flash attention, fp32, non-causal, GQA (4 q-heads per kv-head).
// One block per (q-tile of 64, head, batch). 256 threads.
// Online softmax; O accumulated in registers (4 q-rows x 8 d-cols / thread).
// Output written as attn[b][s][h*128+d]  (i.e. (B,S,H*D) for the dense GEMM).
// ---------------------------------------------------------------------------
__global__ __launch_bounds__(256) void flash_attn(
    const float* __restrict__ Q, const float* __restrict__ Kg,
    const float* __restrict__ Vg, float* __restrict__ Ao)
{
    __shared__ float Qs[64][128];
    __shared__ float Ks[64][132];
    __shared__ float Vs[64][132];
    __shared__ float Ps[64][68];
    __shared__ float mS[64], lS[64], aS[64];

    const int tid = threadIdx.x;
    const int tx = tid & 15, ty = tid >> 4;
    const int qb = blockIdx.x, h = blockIdx.y, b = blockIdx.z;
    const int kh = h >> 2;   // GQA: jnp.repeat(k,4,axis=1) -> head h uses kv h/4

    // load Q tile (scaled by 1/sqrt(D))
    const float* qbase = Q + (((size_t)b * H_ + h) * S_ + qb * 64) * D_;
    const float qscale = 0.08838834764831845f;  // 1/sqrt(128)
#pragma unroll
    for (int t = 0; t < 8; ++t) {
        int e = (tid + 256 * t) * 4;
        float4 v = *(const float4*)(qbase + e);
        int r = e >> 7, d = e & 127;
        v.x *= qscale; v.y *= qscale; v.z *= qscale; v.w *= qscale;
        *(float4*)&Qs[r][d] = v;
    }
    if (tid < 64) { mS[tid] = -1e30f; lS[tid] = 0.f; }

    float o[4][8];
#pragma unroll
    for (int i = 0; i < 4; ++i)
#pragma unroll
        for (int j = 0; j < 8; ++j) o[i][j] = 0.f;

    const float* kbase0 = Kg + (((size_t)b * HK_ + kh) * S_) * D_;
    const float* vbase0 = Vg + (((size_t)b * HK_ + kh) * S_) * D_;

    for (int kb = 0; kb < S_ / 64; ++kb) {
        __syncthreads();   // prev iteration done reading Ks/Vs/Ps (iter 0: Qs written)
        const float* kbase = kbase0 + (size_t)kb * 64 * D_;
        const float* vbase = vbase0 + (size_t)kb * 64 * D_;
#pragma unroll
        for (int t = 0; t < 8; ++t) {
            int e = (tid + 256 * t) * 4;
            int r = e >> 7, d = e & 127;
            *(float4*)&Ks[r][d] = *(const float4*)(kbase + e);
            *(float4*)&Vs[r][d] = *(const float4*)(vbase + e);
        }
        __syncthreads();

        // ---- scores: thread computes 4 q-rows x 4 k-cols; k-col = j*16+tx ----
        float sc[4][4];
#pragma unroll
        for (int i = 0; i < 4; ++i)
#pragma unroll
            for (int j = 0; j < 4; ++j) sc[i][j] = 0.f;

        for (int kk = 0; kk < 128; kk += 4) {
            float4 qv[4], kv[4];
#pragma unroll
            for (int i = 0; i < 4; ++i) qv[i] = *(const float4*)&Qs[ty*4+i][kk];
#pragma unroll
            for (int j = 0; j < 4; ++j) kv[j] = *(const float4*)&Ks[j*16+tx][kk];
#pragma unroll
            for (int i = 0; i < 4; ++i)
#pragma unroll
                for (int j = 0; j < 4; ++j) {
                    sc[i][j] = fmaf(qv[i].x, kv[j].x, sc[i][j]);
                    sc[i][j] = fmaf(qv[i].y, kv[j].y, sc[i][j]);
                    sc[i][j] = fmaf(qv[i].z, kv[j].z, sc[i][j]);
                    sc[i][j] = fmaf(qv[i].w, kv[j].w, sc[i][j]);
                }
        }
#pragma unroll
        for (int i = 0; i < 4; ++i)
#pragma unroll
            for (int j = 0; j < 4; ++j)
                Ps[ty*4+i][j*16+tx] = sc[i][j];
        __syncthreads();

        // ---- online softmax bookkeeping: 4 threads per row ----
        {
            int row = tid >> 2, g = tid & 3;
            float mloc = -1e30f;
#pragma unroll
            for (int c = 0; c < 16; ++c) mloc = fmaxf(mloc, Ps[row][g*16 + c]);
            mloc = fmaxf(mloc, __shfl_xor(mloc, 1));
            mloc = fmaxf(mloc, __shfl_xor(mloc, 2));
            float mold = mS[row];
            float nm = fmaxf(mold, mloc);
            float sl = 0.f;
#pragma unroll
            for (int c = 0; c < 16; ++c) {
                float p = __expf(Ps[row][g*16 + c] - nm);
                Ps[row][g*16 + c] = p;
                sl += p;
            }
            sl += __shfl_xor(sl, 1);
            sl += __shfl_xor(sl, 2);
            if (g == 0) {
                float al = __expf(mold - nm);
                mS[row] = nm;
                lS[row] = lS[row] * al + sl;
                aS[row] = al;
            }
        }
        __syncthreads();

        // ---- rescale O, then O += P * V  (d-col = tx*8 + j) ----
#pragma unroll
        for (int i = 0; i < 4; ++i) {
            float al = aS[ty*4 + i];
#pragma unroll
            for (int j = 0; j < 8; ++j) o[i][j] *= al;
        }
        for (int kk = 0; kk < 64; kk += 4) {
            float pr[4][4];
#pragma unroll
            for (int i = 0; i < 4; ++i)
                *(float4*)&pr[i][0] = *(const float4*)&Ps[ty*4+i][kk];
#pragma unroll
            for (int u = 0; u < 4; ++u) {
                float4 v0 = *(const float4*)&Vs[kk+u][tx*8];
                float4 v1 = *(const float4*)&Vs[kk+u][tx*8+4];
#pragma unroll
                for (int i = 0; i < 4; ++i) {
                    float p = pr[i][u];
                    o[i][0] = fmaf(p, v0.x, o[i][0]);
                    o[i][1] = fmaf(p, v0.y, o[i][1]);
                    o[i][2] = fmaf(p, v0.z, o[i][2]);
                    o[i][3] = fmaf(p, v0.w, o[i][3]);
                    o[i][4] = fmaf(p, v1.x, o[i][4]);
                    o[i][5] = fmaf(p, v1.y, o[i][5]);
                    o[i][6] = fmaf(p, v1.z, o[i][6]);
                    o[i][7] = fmaf(p, v1.w, o[i][7]);
                }
            }
        }
    }

    // ---- epilogue: divide by l, write (B,S,H*D) ----
    float* obase = Ao + ((size_t)b * S_ + qb * 64) * (H_ * D_) + h * D_;
#pragma unroll
    for (int i = 0; i < 4; ++i) {
        int qr = ty*4 + i;
        float inv = 1.f / lS[qr];
        float4 r0, r1;
        r0.x = o[i][0]*inv; r0.y = o[i][1]*inv; r0.z = o[i][2]*inv; r0.w = o[i][3]*inv;
        r1.x = o[i][4]*inv; r1.y = o[i][5]*inv; r1.z = o[i][6]*inv; r1.w = o[i][7]*inv;
        float* p = obase + (size_t)qr * (H_ * D_) + tx*8;
        *(float4*)p       = r0;
        *(float4*)(p + 4) = r1;
    }
}

// ---------------------------------------------------------------------------
extern "C" void kernel_launch(void* const* d_in, const int* in_sizes, int n_in,
                              void* d_out, int out_size, void* d_ws, size_t ws_size,
                              hipStream_t stream)
{
    const float* hidden  = (const float*)d_in[0];
    const float* cosT    = (const float*)d_in[1];
    const float* sinT    = (const float*)d_in[2];
    const float* w_qkv   = (const float*)d_in[3];
    const float* q_ln    = (const float*)d_in[4];
    const float* k_ln    = (const float*)d_in[5];
    const float* w_dense = (const float*)d_in[6];
    float* out = (float*)d_out;

    // workspace layout (floats):
    //   qkv : B*S*3072           = 12,582,912   (reused as attn after norm_rope)
    //   Q   : B*H*S*D            =  8,388,608
    //   K   : B*HK*S*D           =  2,097,152
    //   V   : B*HK*S*D           =  2,097,152
    // total 25,165,824 floats = 96 MiB
    float* qkv = (float*)d_ws;
    float* Q   = qkv + (size_t)B_ * S_ * QKVN;
    float* K   = Q   + (size_t)B_ * H_  * S_ * D_;
    float* V   = K   + (size_t)B_ * HK_ * S_ * D_;
    float* attn = qkv;   // qkv dead after norm_rope; flash never reads it

    // 1) QKV projection: (4096 x 2048) * (3072 x 2048)^T
    sgemm_bt<<<dim3(QKVN / 128, (B_ * S_) / 128), 256, 0, stream>>>(
        hidden, w_qkv, qkv, B_ * S_, QKVN, HID_);

    // 2) RMSNorm + RoPE + split
    norm_rope<<<dim3(NH_, S_, B_), 128, 0, stream>>>(
        qkv, cosT, sinT, q_ln, k_ln, Q, K, V);

    // 3) flash attention -> attn (B,S,H*D)
    flash_attn<<<dim3(S_ / 64, H_, B_), 256, 0, stream>>>(Q, K, V, attn);

    // 4) dense projection: (4096 x 2048) * (2048 x 2048)^T -> out
    sgemm_bt<<<dim3(HID_ / 128, (B_ * S_) / 128), 256, 0, stream>>>(
        attn, w_dense, out, B_ * S_, HID_, H_ * D_);
}

// Round 3
// 1455.644 us; speedup vs baseline: 1.6261x; 1.6261x over previous
//
#include <hip/hip_runtime.h>
#include <hip/hip_bf16.h>
#include <math.h>

#define B_   2
#define S_   2048
#define HID_ 2048
#define H_   16
#define HK_  4
#define D_   128
#define NH_  24          // H + 2*HK
#define QKVN 3072        // NH_ * D_
#define R_   64

typedef __attribute__((ext_vector_type(8))) short sh8;   // 8 bf16 (4 VGPRs) MFMA frag
typedef __attribute__((ext_vector_type(4))) float f4;    // MFMA accumulator

__device__ __forceinline__ short bf16_of(float x) {
    __hip_bfloat16 h = __float2bfloat16(x);
    return *reinterpret_cast<short*>(&h);
}
__device__ __forceinline__ float f_of_bf16(short s) {
    __hip_bfloat16 h = *reinterpret_cast<__hip_bfloat16*>(&s);
    return __bfloat162float(h);
}

// ---------------------------------------------------------------------------
// SGEMM: C[M][N] = A[M][K] * B[N][K]^T   (both A and B are K-contiguous)
// 128x128 tile, BK=8, 256 threads, 8x8 accumulators per thread.
// ---------------------------------------------------------------------------
__global__ __launch_bounds__(256) void sgemm_bt(
    const float* __restrict__ A, const float* __restrict__ Bm,
    float* __restrict__ C, int M, int N, int K)
{
    __shared__ float As[8][132];
    __shared__ float Bs[8][132];

    const int tid = threadIdx.x;
    const int tx = tid & 15, ty = tid >> 4;
    const int m0 = blockIdx.y * 128, n0 = blockIdx.x * 128;

    const int lrow = tid >> 1;
    const int lk   = (tid & 1) * 4;

    const float* Ap = A  + (size_t)(m0 + lrow) * K + lk;
    const float* Bp = Bm + (size_t)(n0 + lrow) * K + lk;

    float acc[8][8];
#pragma unroll
    for (int i = 0; i < 8; ++i)
#pragma unroll
        for (int j = 0; j < 8; ++j) acc[i][j] = 0.f;

    for (int k0 = 0; k0 < K; k0 += 8) {
        float4 av = *(const float4*)(Ap + k0);
        float4 bv = *(const float4*)(Bp + k0);
        __syncthreads();
        As[lk+0][lrow] = av.x; As[lk+1][lrow] = av.y;
        As[lk+2][lrow] = av.z; As[lk+3][lrow] = av.w;
        Bs[lk+0][lrow] = bv.x; Bs[lk+1][lrow] = bv.y;
        Bs[lk+2][lrow] = bv.z; Bs[lk+3][lrow] = bv.w;
        __syncthreads();
#pragma unroll
        for (int kk = 0; kk < 8; ++kk) {
            float a[8], b[8];
            *(float4*)&a[0] = *(const float4*)&As[kk][ty*8];
            *(float4*)&a[4] = *(const float4*)&As[kk][ty*8+4];
            *(float4*)&b[0] = *(const float4*)&Bs[kk][tx*8];
            *(float4*)&b[4] = *(const float4*)&Bs[kk][tx*8+4];
#pragma unroll
            for (int i = 0; i < 8; ++i)
#pragma unroll
                for (int j = 0; j < 8; ++j)
                    acc[i][j] = fmaf(a[i], b[j], acc[i][j]);
        }
    }

#pragma unroll
    for (int i = 0; i < 8; ++i) {
        float* Cp = C + (size_t)(m0 + ty*8 + i) * N + n0 + tx*8;
        *(float4*)Cp       = *(float4*)&acc[i][0];
        *(float4*)(Cp + 4) = *(float4*)&acc[i][4];
    }
}

// ---------------------------------------------------------------------------
// Fused RMSNorm (q,k heads) + partial RoPE (first 64 dims).
// qkv: (B*S, 24, 128):
//   h in [0,16)  -> Q fp32 (B,H,S,D)
//   h in [16,20) -> Khi/Klo bf16-split (B,HK,S,D)
// (V heads are consumed directly from qkv by vtrans.)
// ---------------------------------------------------------------------------
__global__ __launch_bounds__(128) void norm_rope(
    const float* __restrict__ qkv,
    const float* __restrict__ cosT, const float* __restrict__ sinT,
    const float* __restrict__ qw, const float* __restrict__ kw,
    float* __restrict__ Q, short* __restrict__ Khi_g, short* __restrict__ Klo_g)
{
    const int h = blockIdx.x;       // 0..19
    const int s = blockIdx.y;
    const int b = blockIdx.z;
    const int d = threadIdx.x;
    const size_t tok = (size_t)b * S_ + s;

    float x = qkv[(tok * NH_ + h) * D_ + d];
    __shared__ float sh[128];

    sh[d] = x * x;
    __syncthreads();
#pragma unroll
    for (int off = 64; off >= 1; off >>= 1) {
        if (d < off) sh[d] += sh[d + off];
        __syncthreads();
    }
    float var = sh[0] * (1.f / 128.f);
    float scale = rsqrtf(var + 1e-6f);
    const float* w = (h < 16) ? qw : kw;
    float y = x * scale * w[d];
    __syncthreads();
    sh[d] = y;
    __syncthreads();
    if (d < R_) {
        float c  = cosT[tok * R_ + d];
        float sn = sinT[tok * R_ + d];
        float other = (d < 32) ? -sh[d + 32] : sh[d - 32];
        y = y * c + other * sn;
    }

    if (h < 16) {
        Q[(((size_t)b * H_ + h) * S_ + s) * D_ + d] = y;
    } else {
        size_t idx = (((size_t)b * HK_ + (h - 16)) * S_ + s) * D_ + d;
        short hi = bf16_of(y);
        Khi_g[idx] = hi;
        Klo_g[idx] = bf16_of(y - f_of_bf16(hi));
    }
}

// ---------------------------------------------------------------------------
// V transpose: reads V heads straight out of qkv (no norm applied to V),
// writes bf16 Vt (B*HK, D, S).
// ---------------------------------------------------------------------------
__global__ __launch_bounds__(256) void vtrans(
    const float* __restrict__ qkv, short* __restrict__ Vt_g)
{
    __shared__ float Ts[64][132];
    const int tid = threadIdx.x;
    const int sb = blockIdx.x;      // s-tile of 64
    const int bh = blockIdx.y;      // 0..7 = b*HK + kh
    const int b = bh >> 2, kh = bh & 3;

#pragma unroll
    for (int t = 0; t < 8; ++t) {
        int e = (tid + 256 * t) * 4;
        int s = e >> 7, d = e & 127;
        const float* p = qkv + (((size_t)(b * S_ + sb * 64 + s)) * NH_ + 20 + kh) * D_ + d;
        *(float4*)&Ts[s][d] = *(const float4*)p;
    }
    __syncthreads();

#pragma unroll
    for (int tt = 0; tt < 2; ++tt) {
        int dr = (tid >> 2) + 64 * tt;
        int sc = (tid & 3) * 16;
        short tmp[16];
#pragma unroll
        for (int i = 0; i < 16; ++i) tmp[i] = bf16_of(Ts[sc + i][dr]);
        short* outp = Vt_g + ((size_t)bh * D_ + dr) * S_ + sb * 64 + sc;
        *(sh8*)outp       = *(sh8*)&tmp[0];
        *(sh8*)(outp + 8) = *(sh8*)&tmp[8];
    }
}

// ---------------------------------------------------------------------------
// MFMA flash attention. 256 threads = 4 waves; Q-tile 64, KV-tile 64.
// Wave w owns q-row strip [16w,16w+16): softmax fully intra-wave.
// QK^T: split-bf16 3-term (error ~2^-16); PV: plain bf16 (error ~1e-4).
// Q hi/lo fragments in registers; K hi/lo + V^T staged in LDS (61 KB).
// ---------------------------------------------------------------------------
__global__ __launch_bounds__(256) void flash_mfma(
    const float* __restrict__ Q, const short* __restrict__ Khi_g,
    const short* __restrict__ Klo_g, const short* __restrict__ Vt_g,
    float* __restrict__ Ao)
{
    __shared__ short Khi[64][136];   // pad 8 bf16: row stride 272B
    __shared__ short Klo[64][136];
    __shared__ short Vt[128][72];    // V^T: [d][kv]
    __shared__ short Ps[64][72];     // P in A-operand feed layout

    const int tid = threadIdx.x;
    const int wave = tid >> 6, lane = tid & 63;
    const int l15 = lane & 15, l4 = lane >> 4;
    const int qb = blockIdx.x, h = blockIdx.y, b = blockIdx.z;
    const int kh = h >> 2;

    // ---- Q fragments (hi/lo split), A-layout: m=l15 within strip, k=l4*8+j ----
    const float* qrow = Q + (((size_t)b * H_ + h) * S_ + qb * 64 + wave * 16 + l15) * D_;
    const float qscale = 0.08838834764831845f;  // 1/sqrt(128)
    sh8 qh[4], ql[4];
#pragma unroll
    for (int j = 0; j < 4; ++j) {
        int d0 = j * 32 + l4 * 8;
#pragma unroll
        for (int jj = 0; jj < 8; ++jj) {
            float x = qrow[d0 + jj] * qscale;
            short hi = bf16_of(x);
            qh[j][jj] = hi;
            ql[j][jj] = bf16_of(x - f_of_bf16(hi));
        }
    }

    f4 o[8];
#pragma unroll
    for (int t = 0; t < 8; ++t) o[t] = (f4){0.f, 0.f, 0.f, 0.f};
    float m_r[4] = {-1e30f, -1e30f, -1e30f, -1e30f};
    float l_r[4] = {0.f, 0.f, 0.f, 0.f};

    const size_t kvoff = ((size_t)b * HK_ + kh) * S_ * D_;
    const short* khg = Khi_g + kvoff;
    const short* klg = Klo_g + kvoff;
    const short* vtg = Vt_g + kvoff;   // [D][S] per head

    for (int kb = 0; kb < S_ / 64; ++kb) {
        __syncthreads();   // prev tile's LDS reads done
        // ---- stage K hi/lo (row-major) and V^T ----
#pragma unroll
        for (int t = 0; t < 4; ++t) {
            int e = (tid + 256 * t) * 8;
            int r = e >> 7, d = e & 127;
            *(sh8*)&Khi[r][d] = *(const sh8*)(khg + (size_t)(kb * 64 + r) * D_ + d);
            *(sh8*)&Klo[r][d] = *(const sh8*)(klg + (size_t)(kb * 64 + r) * D_ + d);
            int dr = e >> 6, sc = e & 63;
            *(sh8*)&Vt[dr][sc] = *(const sh8*)(vtg + (size_t)dr * S_ + kb * 64 + sc);
        }
        __syncthreads();

        // ---- scores: wave strip (16 rows) x 64 cols = 4 col-tiles ----
        f4 acc[4];
#pragma unroll
        for (int c = 0; c < 4; ++c) acc[c] = (f4){0.f, 0.f, 0.f, 0.f};
#pragma unroll
        for (int j = 0; j < 4; ++j) {
#pragma unroll
            for (int c = 0; c < 4; ++c) {
                sh8 khf = *(const sh8*)&Khi[c * 16 + l15][j * 32 + l4 * 8];
                sh8 klf = *(const sh8*)&Klo[c * 16 + l15][j * 32 + l4 * 8];
                acc[c] = __builtin_amdgcn_mfma_f32_16x16x32_bf16(qh[j], khf, acc[c], 0, 0, 0);
                acc[c] = __builtin_amdgcn_mfma_f32_16x16x32_bf16(qh[j], klf, acc[c], 0, 0, 0);
                acc[c] = __builtin_amdgcn_mfma_f32_16x16x32_bf16(ql[j], khf, acc[c], 0, 0, 0);
            }
        }

        // ---- online softmax, intra-wave (row r_local = 4*l4 + reg) ----
        float p[4][4];     // [c][reg]
        float alpha[4];
#pragma unroll
        for (int r = 0; r < 4; ++r) {
            float mx = fmaxf(fmaxf(acc[0][r], acc[1][r]), fmaxf(acc[2][r], acc[3][r]));
            mx = fmaxf(mx, __shfl_xor(mx, 1));
            mx = fmaxf(mx, __shfl_xor(mx, 2));
            mx = fmaxf(mx, __shfl_xor(mx, 4));
            mx = fmaxf(mx, __shfl_xor(mx, 8));
            float mn = fmaxf(m_r[r], mx);
            alpha[r] = __expf(m_r[r] - mn);
            m_r[r] = mn;
            float sl = 0.f;
#pragma unroll
            for (int c = 0; c < 4; ++c) {
                float e_ = __expf(acc[c][r] - mn);
                p[c][r] = e_;
                sl += e_;
            }
            sl += __shfl_xor(sl, 1);
            sl += __shfl_xor(sl, 2);
            sl += __shfl_xor(sl, 4);
            sl += __shfl_xor(sl, 8);
            l_r[r] = l_r[r] * alpha[r] + sl;
        }
        // write P (bf16) to LDS; rescale O
#pragma unroll
        for (int c = 0; c < 4; ++c)
#pragma unroll
            for (int r = 0; r < 4; ++r)
                Ps[wave * 16 + l4 * 4 + r][c * 16 + l15] = bf16_of(p[c][r]);
#pragma unroll
        for (int t = 0; t < 8; ++t)
#pragma unroll
            for (int r = 0; r < 4; ++r) o[t][r] *= alpha[r];
        __syncthreads();   // Ps visible (wave-local use, barrier for safety)

        // ---- PV: O(16 x 128) += P(16 x 64) * V(64 x 128) ----
#pragma unroll
        for (int s2 = 0; s2 < 2; ++s2) {
            sh8 pf = *(const sh8*)&Ps[wave * 16 + l15][s2 * 32 + l4 * 8];
#pragma unroll
            for (int t = 0; t < 8; ++t) {
                sh8 vf = *(const sh8*)&Vt[t * 16 + l15][s2 * 32 + l4 * 8];
                o[t] = __builtin_amdgcn_mfma_f32_16x16x32_bf16(pf, vf, o[t], 0, 0, 0);
            }
        }
    }

    // ---- epilogue: divide by l, write (B,S,H*D) fp32 ----
    float inv[4];
#pragma unroll
    for (int r = 0; r < 4; ++r) inv[r] = 1.f / l_r[r];
#pragma unroll
    for (int t = 0; t < 8; ++t) {
#pragma unroll
        for (int r = 0; r < 4; ++r) {
            int row = qb * 64 + wave * 16 + l4 * 4 + r;
            Ao[((size_t)b * S_ + row) * (H_ * D_) + h * D_ + t * 16 + l15] = o[t][r] * inv[r];
        }
    }
}

// ---------------------------------------------------------------------------
extern "C" void kernel_launch(void* const* d_in, const int* in_sizes, int n_in,
                              void* d_out, int out_size, void* d_ws, size_t ws_size,
                              hipStream_t stream)
{
    const float* hidden  = (const float*)d_in[0];
    const float* cosT    = (const float*)d_in[1];
    const float* sinT    = (const float*)d_in[2];
    const float* w_qkv   = (const float*)d_in[3];
    const float* q_ln    = (const float*)d_in[4];
    const float* k_ln    = (const float*)d_in[5];
    const float* w_dense = (const float*)d_in[6];
    float* out = (float*)d_out;

    // workspace layout:
    //   qkv : B*S*3072 fp32      = 50.3 MB  (reused as attn after vtrans)
    //   Q   : B*H*S*D fp32       = 33.6 MB
    //   Khi : B*HK*S*D bf16      =  4.2 MB
    //   Klo : B*HK*S*D bf16      =  4.2 MB
    //   Vt  : B*HK*D*S bf16      =  4.2 MB
    // total ~96.5 MB
    float* qkv = (float*)d_ws;
    float* Q   = qkv + (size_t)B_ * S_ * QKVN;
    short* Khi = (short*)(Q + (size_t)B_ * H_ * S_ * D_);
    short* Klo = Khi + (size_t)B_ * HK_ * S_ * D_;
    short* Vt  = Klo + (size_t)B_ * HK_ * S_ * D_;
    float* attn = qkv;   // qkv dead after vtrans; flash never reads it

    // 1) QKV projection (fp32 SGEMM)
    sgemm_bt<<<dim3(QKVN / 128, (B_ * S_) / 128), 256, 0, stream>>>(
        hidden, w_qkv, qkv, B_ * S_, QKVN, HID_);

    // 2) RMSNorm + RoPE; Q fp32, K split-bf16
    norm_rope<<<dim3(20, S_, B_), 128, 0, stream>>>(
        qkv, cosT, sinT, q_ln, k_ln, Q, Khi, Klo);

    // 3) V transpose -> bf16 (B*HK, D, S)
    vtrans<<<dim3(S_ / 64, B_ * HK_), 256, 0, stream>>>(qkv, Vt);

    // 4) MFMA flash attention -> attn (B,S,H*D)
    flash_mfma<<<dim3(S_ / 64, H_, B_), 256, 0, stream>>>(Q, Khi, Klo, Vt, attn);

    // 5) dense projection (fp32 SGEMM)
    sgemm_bt<<<dim3(HID_ / 128, (B_ * S_) / 128), 256, 0, stream>>>(
        attn, w_dense, out, B_ * S_, HID_, H_ * D_);
}

// Round 4
// 708.638 us; speedup vs baseline: 3.3403x; 2.0541x over previous
//
#include <hip/hip_runtime.h>
#include <hip/hip_bf16.h>
#include <math.h>

#define B_   2
#define S_   2048
#define HID_ 2048
#define H_   16
#define HK_  4
#define D_   128
#define NH_  24          // H + 2*HK
#define QKVN 3072        // NH_ * D_
#define R_   64

typedef __attribute__((ext_vector_type(8))) short sh8;   // 8 bf16 (4 VGPRs) MFMA frag
typedef __attribute__((ext_vector_type(4))) short sh4;   // 4 bf16 (8B LDS store)
typedef __attribute__((ext_vector_type(4))) float f4;    // MFMA accumulator

__device__ __forceinline__ short bf16_of(float x) {
    __hip_bfloat16 h = __float2bfloat16(x);
    return *reinterpret_cast<short*>(&h);
}
__device__ __forceinline__ float f_of_bf16(short s) {
    __hip_bfloat16 h = *reinterpret_cast<__hip_bfloat16*>(&s);
    return __bfloat162float(h);
}

// ---------------------------------------------------------------------------
// Split-bf16 MFMA GEMM: C[M][N] = A[M][K] * B[N][K]^T  (fp32 in/out).
// A,B split on the fly into bf16 hi+lo; D = Ah*Bh + Ah*Bl + Al*Bh (fp32 acc).
// 128x128 block tile, BK=32, 256 threads = 4 waves (2x2), wave tile 64x64
// = 4x4 MFMA tiles of 16x16x32. Residual error ~2^-17 rel.
// ---------------------------------------------------------------------------
__global__ __launch_bounds__(256) void gemm_split(
    const float* __restrict__ A, const float* __restrict__ Bm,
    float* __restrict__ C, int M, int N, int K)
{
    __shared__ short Ah[128][40];   // +8 pad: row stride 80B
    __shared__ short Al[128][40];
    __shared__ short Bh[128][40];
    __shared__ short Bl[128][40];

    const int tid = threadIdx.x;
    const int wave = tid >> 6, lane = tid & 63;
    const int l15 = lane & 15, l4 = lane >> 4;
    const int m0 = blockIdx.y * 128, n0 = blockIdx.x * 128;
    const int wm = (wave >> 1) * 64, wn = (wave & 1) * 64;

    f4 acc[16];
#pragma unroll
    for (int t = 0; t < 16; ++t) acc[t] = (f4){0.f, 0.f, 0.f, 0.f};

    for (int k0 = 0; k0 < K; k0 += 32) {
        // ---- global loads: 4 float4 of A + 4 of B per thread ----
        float4 a4[4], b4[4];
#pragma unroll
        for (int i = 0; i < 4; ++i) {
            int idx = tid + 256 * i;            // 0..1023
            int r = idx >> 3, c4 = idx & 7;     // row 0..127, float4-col 0..7
            a4[i] = *(const float4*)(A  + (size_t)(m0 + r) * K + k0 + c4 * 4);
            b4[i] = *(const float4*)(Bm + (size_t)(n0 + r) * K + k0 + c4 * 4);
        }
        __syncthreads();   // previous iteration's fragment reads done
#pragma unroll
        for (int i = 0; i < 4; ++i) {
            int idx = tid + 256 * i;
            int r = idx >> 3, c = (idx & 7) * 4;
            sh4 h, l;
            float v0 = a4[i].x, v1 = a4[i].y, v2 = a4[i].z, v3 = a4[i].w;
            h[0] = bf16_of(v0); l[0] = bf16_of(v0 - f_of_bf16(h[0]));
            h[1] = bf16_of(v1); l[1] = bf16_of(v1 - f_of_bf16(h[1]));
            h[2] = bf16_of(v2); l[2] = bf16_of(v2 - f_of_bf16(h[2]));
            h[3] = bf16_of(v3); l[3] = bf16_of(v3 - f_of_bf16(h[3]));
            *(sh4*)&Ah[r][c] = h;
            *(sh4*)&Al[r][c] = l;
            v0 = b4[i].x; v1 = b4[i].y; v2 = b4[i].z; v3 = b4[i].w;
            h[0] = bf16_of(v0); l[0] = bf16_of(v0 - f_of_bf16(h[0]));
            h[1] = bf16_of(v1); l[1] = bf16_of(v1 - f_of_bf16(h[1]));
            h[2] = bf16_of(v2); l[2] = bf16_of(v2 - f_of_bf16(h[2]));
            h[3] = bf16_of(v3); l[3] = bf16_of(v3 - f_of_bf16(h[3]));
            *(sh4*)&Bh[r][c] = h;
            *(sh4*)&Bl[r][c] = l;
        }
        __syncthreads();

        // ---- fragments: A rows wm+i*16+l15, B rows wn+j*16+l15, k=l4*8 ----
        sh8 ahf[4], alf[4], bhf[4], blf[4];
#pragma unroll
        for (int i = 0; i < 4; ++i) {
            ahf[i] = *(const sh8*)&Ah[wm + i * 16 + l15][l4 * 8];
            alf[i] = *(const sh8*)&Al[wm + i * 16 + l15][l4 * 8];
            bhf[i] = *(const sh8*)&Bh[wn + i * 16 + l15][l4 * 8];
            blf[i] = *(const sh8*)&Bl[wn + i * 16 + l15][l4 * 8];
        }
#pragma unroll
        for (int i = 0; i < 4; ++i)
#pragma unroll
            for (int j = 0; j < 4; ++j) {
                f4 a = acc[i * 4 + j];
                a = __builtin_amdgcn_mfma_f32_16x16x32_bf16(ahf[i], bhf[j], a, 0, 0, 0);
                a = __builtin_amdgcn_mfma_f32_16x16x32_bf16(ahf[i], blf[j], a, 0, 0, 0);
                a = __builtin_amdgcn_mfma_f32_16x16x32_bf16(alf[i], bhf[j], a, 0, 0, 0);
                acc[i * 4 + j] = a;
            }
    }

    // ---- epilogue: D row = l4*4+reg, col = l15 within each 16x16 tile ----
#pragma unroll
    for (int i = 0; i < 4; ++i)
#pragma unroll
        for (int j = 0; j < 4; ++j)
#pragma unroll
            for (int r = 0; r < 4; ++r) {
                int row = m0 + wm + i * 16 + l4 * 4 + r;
                int col = n0 + wn + j * 16 + l15;
                C[(size_t)row * N + col] = acc[i * 4 + j][r];
            }
}

// ---------------------------------------------------------------------------
// Fused RMSNorm (q,k heads) + partial RoPE (first 64 dims).
//   h in [0,16)  -> Q fp32 (B,H,S,D)
//   h in [16,20) -> Khi/Klo bf16-split (B,HK,S,D)
// ---------------------------------------------------------------------------
__global__ __launch_bounds__(128) void norm_rope(
    const float* __restrict__ qkv,
    const float* __restrict__ cosT, const float* __restrict__ sinT,
    const float* __restrict__ qw, const float* __restrict__ kw,
    float* __restrict__ Q, short* __restrict__ Khi_g, short* __restrict__ Klo_g)
{
    const int h = blockIdx.x;       // 0..19
    const int s = blockIdx.y;
    const int b = blockIdx.z;
    const int d = threadIdx.x;
    const size_t tok = (size_t)b * S_ + s;

    float x = qkv[(tok * NH_ + h) * D_ + d];
    __shared__ float sh[128];

    sh[d] = x * x;
    __syncthreads();
#pragma unroll
    for (int off = 64; off >= 1; off >>= 1) {
        if (d < off) sh[d] += sh[d + off];
        __syncthreads();
    }
    float var = sh[0] * (1.f / 128.f);
    float scale = rsqrtf(var + 1e-6f);
    const float* w = (h < 16) ? qw : kw;
    float y = x * scale * w[d];
    __syncthreads();
    sh[d] = y;
    __syncthreads();
    if (d < R_) {
        float c  = cosT[tok * R_ + d];
        float sn = sinT[tok * R_ + d];
        float other = (d < 32) ? -sh[d + 32] : sh[d - 32];
        y = y * c + other * sn;
    }

    if (h < 16) {
        Q[(((size_t)b * H_ + h) * S_ + s) * D_ + d] = y;
    } else {
        size_t idx = (((size_t)b * HK_ + (h - 16)) * S_ + s) * D_ + d;
        short hi = bf16_of(y);
        Khi_g[idx] = hi;
        Klo_g[idx] = bf16_of(y - f_of_bf16(hi));
    }
}

// ---------------------------------------------------------------------------
// V transpose: reads V heads straight out of qkv, writes bf16 Vt (B*HK, D, S).
// ---------------------------------------------------------------------------
__global__ __launch_bounds__(256) void vtrans(
    const float* __restrict__ qkv, short* __restrict__ Vt_g)
{
    __shared__ float Ts[64][132];
    const int tid = threadIdx.x;
    const int sb = blockIdx.x;      // s-tile of 64
    const int bh = blockIdx.y;      // 0..7 = b*HK + kh
    const int b = bh >> 2, kh = bh & 3;

#pragma unroll
    for (int t = 0; t < 8; ++t) {
        int e = (tid + 256 * t) * 4;
        int s = e >> 7, d = e & 127;
        const float* p = qkv + (((size_t)(b * S_ + sb * 64 + s)) * NH_ + 20 + kh) * D_ + d;
        *(float4*)&Ts[s][d] = *(const float4*)p;
    }
    __syncthreads();

#pragma unroll
    for (int tt = 0; tt < 2; ++tt) {
        int dr = (tid >> 2) + 64 * tt;
        int sc = (tid & 3) * 16;
        short tmp[16];
#pragma unroll
        for (int i = 0; i < 16; ++i) tmp[i] = bf16_of(Ts[sc + i][dr]);
        short* outp = Vt_g + ((size_t)bh * D_ + dr) * S_ + sb * 64 + sc;
        *(sh8*)outp       = *(sh8*)&tmp[0];
        *(sh8*)(outp + 8) = *(sh8*)&tmp[8];
    }
}

// ---------------------------------------------------------------------------
// MFMA flash attention. 256 threads = 4 waves; Q-tile 64, KV-tile 64.
// Wave w owns q-row strip [16w,16w+16): softmax fully intra-wave.
// ---------------------------------------------------------------------------
__global__ __launch_bounds__(256) void flash_mfma(
    const float* __restrict__ Q, const short* __restrict__ Khi_g,
    const short* __restrict__ Klo_g, const short* __restrict__ Vt_g,
    float* __restrict__ Ao)
{
    __shared__ short Khi[64][136];
    __shared__ short Klo[64][136];
    __shared__ short Vt[128][72];
    __shared__ short Ps[64][72];

    const int tid = threadIdx.x;
    const int wave = tid >> 6, lane = tid & 63;
    const int l15 = lane & 15, l4 = lane >> 4;
    const int qb = blockIdx.x, h = blockIdx.y, b = blockIdx.z;
    const int kh = h >> 2;

    const float* qrow = Q + (((size_t)b * H_ + h) * S_ + qb * 64 + wave * 16 + l15) * D_;
    const float qscale = 0.08838834764831845f;  // 1/sqrt(128)
    sh8 qh[4], ql[4];
#pragma unroll
    for (int j = 0; j < 4; ++j) {
        int d0 = j * 32 + l4 * 8;
#pragma unroll
        for (int jj = 0; jj < 8; ++jj) {
            float x = qrow[d0 + jj] * qscale;
            short hi = bf16_of(x);
            qh[j][jj] = hi;
            ql[j][jj] = bf16_of(x - f_of_bf16(hi));
        }
    }

    f4 o[8];
#pragma unroll
    for (int t = 0; t < 8; ++t) o[t] = (f4){0.f, 0.f, 0.f, 0.f};
    float m_r[4] = {-1e30f, -1e30f, -1e30f, -1e30f};
    float l_r[4] = {0.f, 0.f, 0.f, 0.f};

    const size_t kvoff = ((size_t)b * HK_ + kh) * S_ * D_;
    const short* khg = Khi_g + kvoff;
    const short* klg = Klo_g + kvoff;
    const short* vtg = Vt_g + kvoff;

    for (int kb = 0; kb < S_ / 64; ++kb) {
        __syncthreads();
#pragma unroll
        for (int t = 0; t < 4; ++t) {
            int e = (tid + 256 * t) * 8;
            int r = e >> 7, d = e & 127;
            *(sh8*)&Khi[r][d] = *(const sh8*)(khg + (size_t)(kb * 64 + r) * D_ + d);
            *(sh8*)&Klo[r][d] = *(const sh8*)(klg + (size_t)(kb * 64 + r) * D_ + d);
            int dr = e >> 6, sc = e & 63;
            *(sh8*)&Vt[dr][sc] = *(const sh8*)(vtg + (size_t)dr * S_ + kb * 64 + sc);
        }
        __syncthreads();

        f4 acc[4];
#pragma unroll
        for (int c = 0; c < 4; ++c) acc[c] = (f4){0.f, 0.f, 0.f, 0.f};
#pragma unroll
        for (int j = 0; j < 4; ++j) {
#pragma unroll
            for (int c = 0; c < 4; ++c) {
                sh8 khf = *(const sh8*)&Khi[c * 16 + l15][j * 32 + l4 * 8];
                sh8 klf = *(const sh8*)&Klo[c * 16 + l15][j * 32 + l4 * 8];
                acc[c] = __builtin_amdgcn_mfma_f32_16x16x32_bf16(qh[j], khf, acc[c], 0, 0, 0);
                acc[c] = __builtin_amdgcn_mfma_f32_16x16x32_bf16(qh[j], klf, acc[c], 0, 0, 0);
                acc[c] = __builtin_amdgcn_mfma_f32_16x16x32_bf16(ql[j], khf, acc[c], 0, 0, 0);
            }
        }

        float p[4][4];
        float alpha[4];
#pragma unroll
        for (int r = 0; r < 4; ++r) {
            float mx = fmaxf(fmaxf(acc[0][r], acc[1][r]), fmaxf(acc[2][r], acc[3][r]));
            mx = fmaxf(mx, __shfl_xor(mx, 1));
            mx = fmaxf(mx, __shfl_xor(mx, 2));
            mx = fmaxf(mx, __shfl_xor(mx, 4));
            mx = fmaxf(mx, __shfl_xor(mx, 8));
            float mn = fmaxf(m_r[r], mx);
            alpha[r] = __expf(m_r[r] - mn);
            m_r[r] = mn;
            float sl = 0.f;
#pragma unroll
            for (int c = 0; c < 4; ++c) {
                float e_ = __expf(acc[c][r] - mn);
                p[c][r] = e_;
                sl += e_;
            }
            sl += __shfl_xor(sl, 1);
            sl += __shfl_xor(sl, 2);
            sl += __shfl_xor(sl, 4);
            sl += __shfl_xor(sl, 8);
            l_r[r] = l_r[r] * alpha[r] + sl;
        }
#pragma unroll
        for (int c = 0; c < 4; ++c)
#pragma unroll
            for (int r = 0; r < 4; ++r)
                Ps[wave * 16 + l4 * 4 + r][c * 16 + l15] = bf16_of(p[c][r]);
#pragma unroll
        for (int t = 0; t < 8; ++t)
#pragma unroll
            for (int r = 0; r < 4; ++r) o[t][r] *= alpha[r];
        __syncthreads();

#pragma unroll
        for (int s2 = 0; s2 < 2; ++s2) {
            sh8 pf = *(const sh8*)&Ps[wave * 16 + l15][s2 * 32 + l4 * 8];
#pragma unroll
            for (int t = 0; t < 8; ++t) {
                sh8 vf = *(const sh8*)&Vt[t * 16 + l15][s2 * 32 + l4 * 8];
                o[t] = __builtin_amdgcn_mfma_f32_16x16x32_bf16(pf, vf, o[t], 0, 0, 0);
            }
        }
    }

    float inv[4];
#pragma unroll
    for (int r = 0; r < 4; ++r) inv[r] = 1.f / l_r[r];
#pragma unroll
    for (int t = 0; t < 8; ++t) {
#pragma unroll
        for (int r = 0; r < 4; ++r) {
            int row = qb * 64 + wave * 16 + l4 * 4 + r;
            Ao[((size_t)b * S_ + row) * (H_ * D_) + h * D_ + t * 16 + l15] = o[t][r] * inv[r];
        }
    }
}

// ---------------------------------------------------------------------------
extern "C" void kernel_launch(void* const* d_in, const int* in_sizes, int n_in,
                              void* d_out, int out_size, void* d_ws, size_t ws_size,
                              hipStream_t stream)
{
    const float* hidden  = (const float*)d_in[0];
    const float* cosT    = (const float*)d_in[1];
    const float* sinT    = (const float*)d_in[2];
    const float* w_qkv   = (const float*)d_in[3];
    const float* q_ln    = (const float*)d_in[4];
    const float* k_ln    = (const float*)d_in[5];
    const float* w_dense = (const float*)d_in[6];
    float* out = (float*)d_out;

    float* qkv = (float*)d_ws;
    float* Q   = qkv + (size_t)B_ * S_ * QKVN;
    short* Khi = (short*)(Q + (size_t)B_ * H_ * S_ * D_);
    short* Klo = Khi + (size_t)B_ * HK_ * S_ * D_;
    short* Vt  = Klo + (size_t)B_ * HK_ * S_ * D_;
    float* attn = qkv;   // qkv dead after vtrans; flash never reads it

    // 1) QKV projection (split-bf16 MFMA GEMM)
    gemm_split<<<dim3(QKVN / 128, (B_ * S_) / 128), 256, 0, stream>>>(
        hidden, w_qkv, qkv, B_ * S_, QKVN, HID_);

    // 2) RMSNorm + RoPE; Q fp32, K split-bf16
    norm_rope<<<dim3(20, S_, B_), 128, 0, stream>>>(
        qkv, cosT, sinT, q_ln, k_ln, Q, Khi, Klo);

    // 3) V transpose -> bf16 (B*HK, D, S)
    vtrans<<<dim3(S_ / 64, B_ * HK_), 256, 0, stream>>>(qkv, Vt);

    // 4) MFMA flash attention -> attn (B,S,H*D)
    flash_mfma<<<dim3(S_ / 64, H_, B_), 256, 0, stream>>>(Q, Khi, Klo, Vt, attn);

    // 5) dense projection (split-bf16 MFMA GEMM)
    gemm_split<<<dim3(HID_ / 128, (B_ * S_) / 128), 256, 0, stream>>>(
        attn, w_dense, out, B_ * S_, HID_, H_ * D_);
}

// Round 5
// 708.098 us; speedup vs baseline: 3.3429x; 1.0008x over previous
//
#include <hip/hip_runtime.h>
#include <hip/hip_bf16.h>
#include <math.h>

#define B_   2
#define S_   2048
#define HID_ 2048
#define H_   16
#define HK_  4
#define D_   128
#define NH_  24          // H + 2*HK
#define QKVN 3072        // NH_ * D_
#define R_   64

typedef __attribute__((ext_vector_type(8))) short sh8;   // 8 bf16 (4 VGPRs) MFMA frag
typedef __attribute__((ext_vector_type(4))) short sh4;   // 4 bf16 (8B LDS store)
typedef __attribute__((ext_vector_type(4))) float f4;    // MFMA accumulator

__device__ __forceinline__ short bf16_of(float x) {
    __hip_bfloat16 h = __float2bfloat16(x);
    return *reinterpret_cast<short*>(&h);
}
__device__ __forceinline__ float f_of_bf16(short s) {
    __hip_bfloat16 h = *reinterpret_cast<__hip_bfloat16*>(&s);
    return __bfloat162float(h);
}

// ---------------------------------------------------------------------------
// Split-bf16 MFMA GEMM: C[M][N] = A[M][K] * B[N][K]^T  (fp32 in/out).
// A,B split on the fly into bf16 hi+lo; D = Ah*Bh + Ah*Bl + Al*Bh (fp32 acc).
// 128x128 block tile, BK=32, 256 threads = 4 waves (2x2), wave tile 64x64.
// ---------------------------------------------------------------------------
__global__ __launch_bounds__(256) void gemm_split(
    const float* __restrict__ A, const float* __restrict__ Bm,
    float* __restrict__ C, int M, int N, int K)
{
    __shared__ short Ah[128][40];   // +8 pad: row stride 80B
    __shared__ short Al[128][40];
    __shared__ short Bh[128][40];
    __shared__ short Bl[128][40];

    const int tid = threadIdx.x;
    const int wave = tid >> 6, lane = tid & 63;
    const int l15 = lane & 15, l4 = lane >> 4;
    const int m0 = blockIdx.y * 128, n0 = blockIdx.x * 128;
    const int wm = (wave >> 1) * 64, wn = (wave & 1) * 64;

    f4 acc[16];
#pragma unroll
    for (int t = 0; t < 16; ++t) acc[t] = (f4){0.f, 0.f, 0.f, 0.f};

    for (int k0 = 0; k0 < K; k0 += 32) {
        float4 a4[4], b4[4];
#pragma unroll
        for (int i = 0; i < 4; ++i) {
            int idx = tid + 256 * i;
            int r = idx >> 3, c4 = idx & 7;
            a4[i] = *(const float4*)(A  + (size_t)(m0 + r) * K + k0 + c4 * 4);
            b4[i] = *(const float4*)(Bm + (size_t)(n0 + r) * K + k0 + c4 * 4);
        }
        __syncthreads();
#pragma unroll
        for (int i = 0; i < 4; ++i) {
            int idx = tid + 256 * i;
            int r = idx >> 3, c = (idx & 7) * 4;
            sh4 h, l;
            float v0 = a4[i].x, v1 = a4[i].y, v2 = a4[i].z, v3 = a4[i].w;
            h[0] = bf16_of(v0); l[0] = bf16_of(v0 - f_of_bf16(h[0]));
            h[1] = bf16_of(v1); l[1] = bf16_of(v1 - f_of_bf16(h[1]));
            h[2] = bf16_of(v2); l[2] = bf16_of(v2 - f_of_bf16(h[2]));
            h[3] = bf16_of(v3); l[3] = bf16_of(v3 - f_of_bf16(h[3]));
            *(sh4*)&Ah[r][c] = h;
            *(sh4*)&Al[r][c] = l;
            v0 = b4[i].x; v1 = b4[i].y; v2 = b4[i].z; v3 = b4[i].w;
            h[0] = bf16_of(v0); l[0] = bf16_of(v0 - f_of_bf16(h[0]));
            h[1] = bf16_of(v1); l[1] = bf16_of(v1 - f_of_bf16(h[1]));
            h[2] = bf16_of(v2); l[2] = bf16_of(v2 - f_of_bf16(h[2]));
            h[3] = bf16_of(v3); l[3] = bf16_of(v3 - f_of_bf16(h[3]));
            *(sh4*)&Bh[r][c] = h;
            *(sh4*)&Bl[r][c] = l;
        }
        __syncthreads();

        sh8 ahf[4], alf[4], bhf[4], blf[4];
#pragma unroll
        for (int i = 0; i < 4; ++i) {
            ahf[i] = *(const sh8*)&Ah[wm + i * 16 + l15][l4 * 8];
            alf[i] = *(const sh8*)&Al[wm + i * 16 + l15][l4 * 8];
            bhf[i] = *(const sh8*)&Bh[wn + i * 16 + l15][l4 * 8];
            blf[i] = *(const sh8*)&Bl[wn + i * 16 + l15][l4 * 8];
        }
#pragma unroll
        for (int i = 0; i < 4; ++i)
#pragma unroll
            for (int j = 0; j < 4; ++j) {
                f4 a = acc[i * 4 + j];
                a = __builtin_amdgcn_mfma_f32_16x16x32_bf16(ahf[i], bhf[j], a, 0, 0, 0);
                a = __builtin_amdgcn_mfma_f32_16x16x32_bf16(ahf[i], blf[j], a, 0, 0, 0);
                a = __builtin_amdgcn_mfma_f32_16x16x32_bf16(alf[i], bhf[j], a, 0, 0, 0);
                acc[i * 4 + j] = a;
            }
    }

#pragma unroll
    for (int i = 0; i < 4; ++i)
#pragma unroll
        for (int j = 0; j < 4; ++j)
#pragma unroll
            for (int r = 0; r < 4; ++r) {
                int row = m0 + wm + i * 16 + l4 * 4 + r;
                int col = n0 + wn + j * 16 + l15;
                C[(size_t)row * N + col] = acc[i * 4 + j][r];
            }
}

// ---------------------------------------------------------------------------
// Fused RMSNorm (q,k heads) + partial RoPE (first 64 dims).
//   h in [0,16)  -> Q fp32 (B,H,S,D)
//   h in [16,20) -> Khi/Klo bf16-split (B,HK,S,D)
// ---------------------------------------------------------------------------
__global__ __launch_bounds__(128) void norm_rope(
    const float* __restrict__ qkv,
    const float* __restrict__ cosT, const float* __restrict__ sinT,
    const float* __restrict__ qw, const float* __restrict__ kw,
    float* __restrict__ Q, short* __restrict__ Khi_g, short* __restrict__ Klo_g)
{
    const int h = blockIdx.x;       // 0..19
    const int s = blockIdx.y;
    const int b = blockIdx.z;
    const int d = threadIdx.x;
    const size_t tok = (size_t)b * S_ + s;

    float x = qkv[(tok * NH_ + h) * D_ + d];
    __shared__ float sh[128];

    sh[d] = x * x;
    __syncthreads();
#pragma unroll
    for (int off = 64; off >= 1; off >>= 1) {
        if (d < off) sh[d] += sh[d + off];
        __syncthreads();
    }
    float var = sh[0] * (1.f / 128.f);
    float scale = rsqrtf(var + 1e-6f);
    const float* w = (h < 16) ? qw : kw;
    float y = x * scale * w[d];
    __syncthreads();
    sh[d] = y;
    __syncthreads();
    if (d < R_) {
        float c  = cosT[tok * R_ + d];
        float sn = sinT[tok * R_ + d];
        float other = (d < 32) ? -sh[d + 32] : sh[d - 32];
        y = y * c + other * sn;
    }

    if (h < 16) {
        Q[(((size_t)b * H_ + h) * S_ + s) * D_ + d] = y;
    } else {
        size_t idx = (((size_t)b * HK_ + (h - 16)) * S_ + s) * D_ + d;
        short hi = bf16_of(y);
        Khi_g[idx] = hi;
        Klo_g[idx] = bf16_of(y - f_of_bf16(hi));
    }
}

// ---------------------------------------------------------------------------
// V transpose: reads V heads straight out of qkv, writes bf16 Vt (B*HK, D, S).
// ---------------------------------------------------------------------------
__global__ __launch_bounds__(256) void vtrans(
    const float* __restrict__ qkv, short* __restrict__ Vt_g)
{
    __shared__ float Ts[64][132];
    const int tid = threadIdx.x;
    const int sb = blockIdx.x;
    const int bh = blockIdx.y;
    const int b = bh >> 2, kh = bh & 3;

#pragma unroll
    for (int t = 0; t < 8; ++t) {
        int e = (tid + 256 * t) * 4;
        int s = e >> 7, d = e & 127;
        const float* p = qkv + (((size_t)(b * S_ + sb * 64 + s)) * NH_ + 20 + kh) * D_ + d;
        *(float4*)&Ts[s][d] = *(const float4*)p;
    }
    __syncthreads();

#pragma unroll
    for (int tt = 0; tt < 2; ++tt) {
        int dr = (tid >> 2) + 64 * tt;
        int sc = (tid & 3) * 16;
        short tmp[16];
#pragma unroll
        for (int i = 0; i < 16; ++i) tmp[i] = bf16_of(Ts[sc + i][dr]);
        short* outp = Vt_g + ((size_t)bh * D_ + dr) * S_ + sb * 64 + sc;
        *(sh8*)outp       = *(sh8*)&tmp[0];
        *(sh8*)(outp + 8) = *(sh8*)&tmp[8];
    }
}

// ---------------------------------------------------------------------------
// MFMA flash attention. 256 threads = 4 waves; Q-tile 128, KV-tile 64.
// Wave w owns q-rows [32w, 32w+32) as two 16-row MFMA strips (i = 0,1):
// softmax fully intra-wave; K/V fragment LDS reads shared across both strips.
// QK^T: split-bf16 3-term; PV: plain bf16. LDS 70 KB -> 2 blocks/CU.
// ---------------------------------------------------------------------------
__global__ __launch_bounds__(256, 2) void flash_mfma(
    const float* __restrict__ Q, const short* __restrict__ Khi_g,
    const short* __restrict__ Klo_g, const short* __restrict__ Vt_g,
    float* __restrict__ Ao)
{
    __shared__ short Khi[64][136];   // pad 8: row stride 272B
    __shared__ short Klo[64][136];
    __shared__ short Vt[128][72];    // V^T: [d][kv]
    __shared__ short Ps[128][72];    // P in A-operand feed layout

    const int tid = threadIdx.x;
    const int wave = tid >> 6, lane = tid & 63;
    const int l15 = lane & 15, l4 = lane >> 4;
    const int qb = blockIdx.x, h = blockIdx.y, b = blockIdx.z;
    const int kh = h >> 2;

    // ---- Q fragments (hi/lo split) for both 16-row strips ----
    const float qscale = 0.08838834764831845f;  // 1/sqrt(128)
    sh8 qh[2][4], ql[2][4];
#pragma unroll
    for (int i = 0; i < 2; ++i) {
        const float* qrow = Q + (((size_t)b * H_ + h) * S_ + qb * 128 + wave * 32 + i * 16 + l15) * D_;
#pragma unroll
        for (int j = 0; j < 4; ++j) {
            int d0 = j * 32 + l4 * 8;
#pragma unroll
            for (int jj = 0; jj < 8; ++jj) {
                float x = qrow[d0 + jj] * qscale;
                short hi = bf16_of(x);
                qh[i][j][jj] = hi;
                ql[i][j][jj] = bf16_of(x - f_of_bf16(hi));
            }
        }
    }

    f4 o[2][8];
#pragma unroll
    for (int i = 0; i < 2; ++i)
#pragma unroll
        for (int t = 0; t < 8; ++t) o[i][t] = (f4){0.f, 0.f, 0.f, 0.f};
    float m_r[2][4] = {{-1e30f, -1e30f, -1e30f, -1e30f}, {-1e30f, -1e30f, -1e30f, -1e30f}};
    float l_r[2][4] = {{0.f, 0.f, 0.f, 0.f}, {0.f, 0.f, 0.f, 0.f}};

    const size_t kvoff = ((size_t)b * HK_ + kh) * S_ * D_;
    const short* khg = Khi_g + kvoff;
    const short* klg = Klo_g + kvoff;
    const short* vtg = Vt_g + kvoff;

    for (int kb = 0; kb < S_ / 64; ++kb) {
        __syncthreads();   // prev tile's LDS reads done
#pragma unroll
        for (int t = 0; t < 4; ++t) {
            int e = (tid + 256 * t) * 8;
            int r = e >> 7, d = e & 127;
            *(sh8*)&Khi[r][d] = *(const sh8*)(khg + (size_t)(kb * 64 + r) * D_ + d);
            *(sh8*)&Klo[r][d] = *(const sh8*)(klg + (size_t)(kb * 64 + r) * D_ + d);
            int dr = e >> 6, sc = e & 63;
            *(sh8*)&Vt[dr][sc] = *(const sh8*)(vtg + (size_t)dr * S_ + kb * 64 + sc);
        }
        __syncthreads();

        // ---- scores: 2 strips x (16 x 64); K frag reads shared across strips ----
        f4 acc[2][4];
#pragma unroll
        for (int i = 0; i < 2; ++i)
#pragma unroll
            for (int c = 0; c < 4; ++c) acc[i][c] = (f4){0.f, 0.f, 0.f, 0.f};
#pragma unroll
        for (int j = 0; j < 4; ++j) {
#pragma unroll
            for (int c = 0; c < 4; ++c) {
                sh8 khf = *(const sh8*)&Khi[c * 16 + l15][j * 32 + l4 * 8];
                sh8 klf = *(const sh8*)&Klo[c * 16 + l15][j * 32 + l4 * 8];
#pragma unroll
                for (int i = 0; i < 2; ++i) {
                    acc[i][c] = __builtin_amdgcn_mfma_f32_16x16x32_bf16(qh[i][j], khf, acc[i][c], 0, 0, 0);
                    acc[i][c] = __builtin_amdgcn_mfma_f32_16x16x32_bf16(qh[i][j], klf, acc[i][c], 0, 0, 0);
                    acc[i][c] = __builtin_amdgcn_mfma_f32_16x16x32_bf16(ql[i][j], khf, acc[i][c], 0, 0, 0);
                }
            }
        }

        // ---- online softmax per strip, intra-wave ----
#pragma unroll
        for (int i = 0; i < 2; ++i) {
            float p[4][4];
            float alpha[4];
#pragma unroll
            for (int r = 0; r < 4; ++r) {
                float mx = fmaxf(fmaxf(acc[i][0][r], acc[i][1][r]), fmaxf(acc[i][2][r], acc[i][3][r]));
                mx = fmaxf(mx, __shfl_xor(mx, 1));
                mx = fmaxf(mx, __shfl_xor(mx, 2));
                mx = fmaxf(mx, __shfl_xor(mx, 4));
                mx = fmaxf(mx, __shfl_xor(mx, 8));
                float mn = fmaxf(m_r[i][r], mx);
                alpha[r] = __expf(m_r[i][r] - mn);
                m_r[i][r] = mn;
                float sl = 0.f;
#pragma unroll
                for (int c = 0; c < 4; ++c) {
                    float e_ = __expf(acc[i][c][r] - mn);
                    p[c][r] = e_;
                    sl += e_;
                }
                sl += __shfl_xor(sl, 1);
                sl += __shfl_xor(sl, 2);
                sl += __shfl_xor(sl, 4);
                sl += __shfl_xor(sl, 8);
                l_r[i][r] = l_r[i][r] * alpha[r] + sl;
            }
#pragma unroll
            for (int c = 0; c < 4; ++c)
#pragma unroll
                for (int r = 0; r < 4; ++r)
                    Ps[wave * 32 + i * 16 + l4 * 4 + r][c * 16 + l15] = bf16_of(p[c][r]);
#pragma unroll
            for (int t = 0; t < 8; ++t)
#pragma unroll
                for (int r = 0; r < 4; ++r) o[i][t][r] *= alpha[r];
        }
        // NOTE: no barrier here — Ps rows are strictly wave-local (same wave
        // writes and reads them); ds-op ordering within a wave suffices.

        // ---- PV: per strip O(16x128) += P(16x64) * V(64x128); V reads shared ----
#pragma unroll
        for (int s2 = 0; s2 < 2; ++s2) {
            sh8 pf0 = *(const sh8*)&Ps[wave * 32 + l15][s2 * 32 + l4 * 8];
            sh8 pf1 = *(const sh8*)&Ps[wave * 32 + 16 + l15][s2 * 32 + l4 * 8];
#pragma unroll
            for (int t = 0; t < 8; ++t) {
                sh8 vf = *(const sh8*)&Vt[t * 16 + l15][s2 * 32 + l4 * 8];
                o[0][t] = __builtin_amdgcn_mfma_f32_16x16x32_bf16(pf0, vf, o[0][t], 0, 0, 0);
                o[1][t] = __builtin_amdgcn_mfma_f32_16x16x32_bf16(pf1, vf, o[1][t], 0, 0, 0);
            }
        }
    }

    // ---- epilogue ----
#pragma unroll
    for (int i = 0; i < 2; ++i) {
        float inv[4];
#pragma unroll
        for (int r = 0; r < 4; ++r) inv[r] = 1.f / l_r[i][r];
#pragma unroll
        for (int t = 0; t < 8; ++t) {
#pragma unroll
            for (int r = 0; r < 4; ++r) {
                int row = qb * 128 + wave * 32 + i * 16 + l4 * 4 + r;
                Ao[((size_t)b * S_ + row) * (H_ * D_) + h * D_ + t * 16 + l15] = o[i][t][r] * inv[r];
            }
        }
    }
}

// ---------------------------------------------------------------------------
extern "C" void kernel_launch(void* const* d_in, const int* in_sizes, int n_in,
                              void* d_out, int out_size, void* d_ws, size_t ws_size,
                              hipStream_t stream)
{
    const float* hidden  = (const float*)d_in[0];
    const float* cosT    = (const float*)d_in[1];
    const float* sinT    = (const float*)d_in[2];
    const float* w_qkv   = (const float*)d_in[3];
    const float* q_ln    = (const float*)d_in[4];
    const float* k_ln    = (const float*)d_in[5];
    const float* w_dense = (const float*)d_in[6];
    float* out = (float*)d_out;

    float* qkv = (float*)d_ws;
    float* Q   = qkv + (size_t)B_ * S_ * QKVN;
    short* Khi = (short*)(Q + (size_t)B_ * H_ * S_ * D_);
    short* Klo = Khi + (size_t)B_ * HK_ * S_ * D_;
    short* Vt  = Klo + (size_t)B_ * HK_ * S_ * D_;
    float* attn = qkv;   // qkv dead after vtrans; flash never reads it

    // 1) QKV projection (split-bf16 MFMA GEMM)
    gemm_split<<<dim3(QKVN / 128, (B_ * S_) / 128), 256, 0, stream>>>(
        hidden, w_qkv, qkv, B_ * S_, QKVN, HID_);

    // 2) RMSNorm + RoPE; Q fp32, K split-bf16
    norm_rope<<<dim3(20, S_, B_), 128, 0, stream>>>(
        qkv, cosT, sinT, q_ln, k_ln, Q, Khi, Klo);

    // 3) V transpose -> bf16 (B*HK, D, S)
    vtrans<<<dim3(S_ / 64, B_ * HK_), 256, 0, stream>>>(qkv, Vt);

    // 4) MFMA flash attention (Q-tile 128) -> attn (B,S,H*D)
    flash_mfma<<<dim3(S_ / 128, H_, B_), 256, 0, stream>>>(Q, Khi, Klo, Vt, attn);

    // 5) dense projection (split-bf16 MFMA GEMM)
    gemm_split<<<dim3(HID_ / 128, (B_ * S_) / 128), 256, 0, stream>>>(
        attn, w_dense, out, B_ * S_, HID_, H_ * D_);
}

// Round 6
// 621.711 us; speedup vs baseline: 3.8074x; 1.1389x over previous
//
#include <hip/hip_runtime.h>
#include <hip/hip_bf16.h>
#include <math.h>

#define B_   2
#define S_   2048
#define HID_ 2048
#define H_   16
#define HK_  4
#define D_   128
#define NH_  24          // H + 2*HK
#define QKVN 3072        // NH_ * D_
#define R_   64

typedef __attribute__((ext_vector_type(8))) short sh8;   // 8 bf16 (4 VGPRs) MFMA frag
typedef __attribute__((ext_vector_type(4))) short sh4;   // 4 bf16 (8B LDS store)
typedef __attribute__((ext_vector_type(4))) float f4;    // MFMA accumulator

__device__ __forceinline__ short bf16_of(float x) {
    __hip_bfloat16 h = __float2bfloat16(x);
    return *reinterpret_cast<short*>(&h);
}
__device__ __forceinline__ float f_of_bf16(short s) {
    __hip_bfloat16 h = *reinterpret_cast<__hip_bfloat16*>(&s);
    return __bfloat162float(h);
}

// ---------------------------------------------------------------------------
// Split-bf16 MFMA GEMM: C[M][N] = A[M][K] * B[N][K]^T  (fp32 in/out).
// A,B split on the fly into bf16 hi+lo; D = Ah*Bh + Ah*Bl + Al*Bh (fp32 acc).
// 128x128 block tile, BK=32, 256 threads = 4 waves (2x2), wave tile 64x64.
// ---------------------------------------------------------------------------
__global__ __launch_bounds__(256) void gemm_split(
    const float* __restrict__ A, const float* __restrict__ Bm,
    float* __restrict__ C, int M, int N, int K)
{
    __shared__ short Ah[128][40];   // +8 pad: row stride 80B
    __shared__ short Al[128][40];
    __shared__ short Bh[128][40];
    __shared__ short Bl[128][40];

    const int tid = threadIdx.x;
    const int wave = tid >> 6, lane = tid & 63;
    const int l15 = lane & 15, l4 = lane >> 4;
    const int m0 = blockIdx.y * 128, n0 = blockIdx.x * 128;
    const int wm = (wave >> 1) * 64, wn = (wave & 1) * 64;

    f4 acc[16];
#pragma unroll
    for (int t = 0; t < 16; ++t) acc[t] = (f4){0.f, 0.f, 0.f, 0.f};

    for (int k0 = 0; k0 < K; k0 += 32) {
        float4 a4[4], b4[4];
#pragma unroll
        for (int i = 0; i < 4; ++i) {
            int idx = tid + 256 * i;
            int r = idx >> 3, c4 = idx & 7;
            a4[i] = *(const float4*)(A  + (size_t)(m0 + r) * K + k0 + c4 * 4);
            b4[i] = *(const float4*)(Bm + (size_t)(n0 + r) * K + k0 + c4 * 4);
        }
        __syncthreads();
#pragma unroll
        for (int i = 0; i < 4; ++i) {
            int idx = tid + 256 * i;
            int r = idx >> 3, c = (idx & 7) * 4;
            sh4 h, l;
            float v0 = a4[i].x, v1 = a4[i].y, v2 = a4[i].z, v3 = a4[i].w;
            h[0] = bf16_of(v0); l[0] = bf16_of(v0 - f_of_bf16(h[0]));
            h[1] = bf16_of(v1); l[1] = bf16_of(v1 - f_of_bf16(h[1]));
            h[2] = bf16_of(v2); l[2] = bf16_of(v2 - f_of_bf16(h[2]));
            h[3] = bf16_of(v3); l[3] = bf16_of(v3 - f_of_bf16(h[3]));
            *(sh4*)&Ah[r][c] = h;
            *(sh4*)&Al[r][c] = l;
            v0 = b4[i].x; v1 = b4[i].y; v2 = b4[i].z; v3 = b4[i].w;
            h[0] = bf16_of(v0); l[0] = bf16_of(v0 - f_of_bf16(h[0]));
            h[1] = bf16_of(v1); l[1] = bf16_of(v1 - f_of_bf16(h[1]));
            h[2] = bf16_of(v2); l[2] = bf16_of(v2 - f_of_bf16(h[2]));
            h[3] = bf16_of(v3); l[3] = bf16_of(v3 - f_of_bf16(h[3]));
            *(sh4*)&Bh[r][c] = h;
            *(sh4*)&Bl[r][c] = l;
        }
        __syncthreads();

        sh8 ahf[4], alf[4], bhf[4], blf[4];
#pragma unroll
        for (int i = 0; i < 4; ++i) {
            ahf[i] = *(const sh8*)&Ah[wm + i * 16 + l15][l4 * 8];
            alf[i] = *(const sh8*)&Al[wm + i * 16 + l15][l4 * 8];
            bhf[i] = *(const sh8*)&Bh[wn + i * 16 + l15][l4 * 8];
            blf[i] = *(const sh8*)&Bl[wn + i * 16 + l15][l4 * 8];
        }
#pragma unroll
        for (int i = 0; i < 4; ++i)
#pragma unroll
            for (int j = 0; j < 4; ++j) {
                f4 a = acc[i * 4 + j];
                a = __builtin_amdgcn_mfma_f32_16x16x32_bf16(ahf[i], bhf[j], a, 0, 0, 0);
                a = __builtin_amdgcn_mfma_f32_16x16x32_bf16(ahf[i], blf[j], a, 0, 0, 0);
                a = __builtin_amdgcn_mfma_f32_16x16x32_bf16(alf[i], bhf[j], a, 0, 0, 0);
                acc[i * 4 + j] = a;
            }
    }

#pragma unroll
    for (int i = 0; i < 4; ++i)
#pragma unroll
        for (int j = 0; j < 4; ++j)
#pragma unroll
            for (int r = 0; r < 4; ++r) {
                int row = m0 + wm + i * 16 + l4 * 4 + r;
                int col = n0 + wn + j * 16 + l15;
                C[(size_t)row * N + col] = acc[i * 4 + j][r];
            }
}

// ---------------------------------------------------------------------------
// Fused RMSNorm (q,k heads) + partial RoPE (first 64 dims).
//   h in [0,16)  -> Q fp32 (B,H,S,D)
//   h in [16,20) -> Khi/Klo bf16-split (B,HK,S,D)
// ---------------------------------------------------------------------------
__global__ __launch_bounds__(128) void norm_rope(
    const float* __restrict__ qkv,
    const float* __restrict__ cosT, const float* __restrict__ sinT,
    const float* __restrict__ qw, const float* __restrict__ kw,
    float* __restrict__ Q, short* __restrict__ Khi_g, short* __restrict__ Klo_g)
{
    const int h = blockIdx.x;       // 0..19
    const int s = blockIdx.y;
    const int b = blockIdx.z;
    const int d = threadIdx.x;
    const size_t tok = (size_t)b * S_ + s;

    float x = qkv[(tok * NH_ + h) * D_ + d];
    __shared__ float sh[128];

    sh[d] = x * x;
    __syncthreads();
#pragma unroll
    for (int off = 64; off >= 1; off >>= 1) {
        if (d < off) sh[d] += sh[d + off];
        __syncthreads();
    }
    float var = sh[0] * (1.f / 128.f);
    float scale = rsqrtf(var + 1e-6f);
    const float* w = (h < 16) ? qw : kw;
    float y = x * scale * w[d];
    __syncthreads();
    sh[d] = y;
    __syncthreads();
    if (d < R_) {
        float c  = cosT[tok * R_ + d];
        float sn = sinT[tok * R_ + d];
        float other = (d < 32) ? -sh[d + 32] : sh[d - 32];
        y = y * c + other * sn;
    }

    if (h < 16) {
        Q[(((size_t)b * H_ + h) * S_ + s) * D_ + d] = y;
    } else {
        size_t idx = (((size_t)b * HK_ + (h - 16)) * S_ + s) * D_ + d;
        short hi = bf16_of(y);
        Khi_g[idx] = hi;
        Klo_g[idx] = bf16_of(y - f_of_bf16(hi));
    }
}

// ---------------------------------------------------------------------------
// V transpose: reads V heads straight out of qkv, writes bf16 Vt (B*HK, D, S).
// ---------------------------------------------------------------------------
__global__ __launch_bounds__(256) void vtrans(
    const float* __restrict__ qkv, short* __restrict__ Vt_g)
{
    __shared__ float Ts[64][132];
    const int tid = threadIdx.x;
    const int sb = blockIdx.x;
    const int bh = blockIdx.y;
    const int b = bh >> 2, kh = bh & 3;

#pragma unroll
    for (int t = 0; t < 8; ++t) {
        int e = (tid + 256 * t) * 4;
        int s = e >> 7, d = e & 127;
        const float* p = qkv + (((size_t)(b * S_ + sb * 64 + s)) * NH_ + 20 + kh) * D_ + d;
        *(float4*)&Ts[s][d] = *(const float4*)p;
    }
    __syncthreads();

#pragma unroll
    for (int tt = 0; tt < 2; ++tt) {
        int dr = (tid >> 2) + 64 * tt;
        int sc = (tid & 3) * 16;
        short tmp[16];
#pragma unroll
        for (int i = 0; i < 16; ++i) tmp[i] = bf16_of(Ts[sc + i][dr]);
        short* outp = Vt_g + ((size_t)bh * D_ + dr) * S_ + sb * 64 + sc;
        *(sh8*)outp       = *(sh8*)&tmp[0];
        *(sh8*)(outp + 8) = *(sh8*)&tmp[8];
    }
}

// ---------------------------------------------------------------------------
// MFMA flash attention, softmax-free-max variant. 256 threads = 4 waves;
// Q-tile 128, KV-tile 64. Wave w owns q-rows [32w,32w+32) as two 16-row
// strips. Scores are bounded (RMS-normed q,k: |s| <= sqrt(128) ~ 11.4), so
// we use a FIXED softmax max of 0: p = exp(s) directly, per-lane partial
// row-sums, one cross-lane reduction at the epilogue. No running max, no
// alpha rescale, no per-tile shuffles. K/V staged via register prefetch
// (tile kb+1 loads issue during tile kb compute).
// ---------------------------------------------------------------------------
__global__ __launch_bounds__(256, 2) void flash_mfma(
    const float* __restrict__ Q, const short* __restrict__ Khi_g,
    const short* __restrict__ Klo_g, const short* __restrict__ Vt_g,
    float* __restrict__ Ao)
{
    __shared__ short Khi[64][136];   // pad 8: row stride 272B
    __shared__ short Klo[64][136];
    __shared__ short Vt[128][72];    // V^T: [d][kv]
    __shared__ short Ps[128][72];    // P in A-operand feed layout

    const int tid = threadIdx.x;
    const int wave = tid >> 6, lane = tid & 63;
    const int l15 = lane & 15, l4 = lane >> 4;
    const int qb = blockIdx.x, h = blockIdx.y, b = blockIdx.z;
    const int kh = h >> 2;

    // ---- Q fragments (hi/lo split) for both 16-row strips ----
    const float qscale = 0.08838834764831845f;  // 1/sqrt(128)
    sh8 qh[2][4], ql[2][4];
#pragma unroll
    for (int i = 0; i < 2; ++i) {
        const float* qrow = Q + (((size_t)b * H_ + h) * S_ + qb * 128 + wave * 32 + i * 16 + l15) * D_;
#pragma unroll
        for (int j = 0; j < 4; ++j) {
            int d0 = j * 32 + l4 * 8;
#pragma unroll
            for (int jj = 0; jj < 8; ++jj) {
                float x = qrow[d0 + jj] * qscale;
                short hi = bf16_of(x);
                qh[i][j][jj] = hi;
                ql[i][j][jj] = bf16_of(x - f_of_bf16(hi));
            }
        }
    }

    f4 o[2][8];
#pragma unroll
    for (int i = 0; i < 2; ++i)
#pragma unroll
        for (int t = 0; t < 8; ++t) o[i][t] = (f4){0.f, 0.f, 0.f, 0.f};
    float l_part[2][4] = {{0.f, 0.f, 0.f, 0.f}, {0.f, 0.f, 0.f, 0.f}};

    const size_t kvoff = ((size_t)b * HK_ + kh) * S_ * D_;
    const short* khg = Khi_g + kvoff;
    const short* klg = Klo_g + kvoff;
    const short* vtg = Vt_g + kvoff;

    // per-thread staging addresses (4 chunks x {Khi,Klo,Vt})
    int srow[4], scol[4], vrow[4], vcol[4];
#pragma unroll
    for (int t = 0; t < 4; ++t) {
        int e = (tid + 256 * t) * 8;
        srow[t] = e >> 7; scol[t] = e & 127;   // K: row 0..63, col 0..127
        vrow[t] = e >> 6; vcol[t] = e & 63;    // Vt: row 0..127, col 0..63
    }

    // ---- prefetch tile 0 into registers ----
    sh8 kh_r[4], kl_r[4], vt_r[4];
#pragma unroll
    for (int t = 0; t < 4; ++t) {
        kh_r[t] = *(const sh8*)(khg + (size_t)srow[t] * D_ + scol[t]);
        kl_r[t] = *(const sh8*)(klg + (size_t)srow[t] * D_ + scol[t]);
        vt_r[t] = *(const sh8*)(vtg + (size_t)vrow[t] * S_ + vcol[t]);
    }

    for (int kb = 0; kb < S_ / 64; ++kb) {
        __syncthreads();   // prev tile's LDS reads done
        // ---- commit prefetched tile kb to LDS ----
#pragma unroll
        for (int t = 0; t < 4; ++t) {
            *(sh8*)&Khi[srow[t]][scol[t]] = kh_r[t];
            *(sh8*)&Klo[srow[t]][scol[t]] = kl_r[t];
            *(sh8*)&Vt[vrow[t]][vcol[t]]  = vt_r[t];
        }
        // ---- issue global loads for tile kb+1 (in flight during compute) ----
        if (kb + 1 < S_ / 64) {
            int off = (kb + 1) * 64;
#pragma unroll
            for (int t = 0; t < 4; ++t) {
                kh_r[t] = *(const sh8*)(khg + (size_t)(off + srow[t]) * D_ + scol[t]);
                kl_r[t] = *(const sh8*)(klg + (size_t)(off + srow[t]) * D_ + scol[t]);
                vt_r[t] = *(const sh8*)(vtg + (size_t)vrow[t] * S_ + off + vcol[t]);
            }
        }
        __syncthreads();

        // ---- scores: 2 strips x (16 x 64); K frag reads shared across strips ----
        f4 acc[2][4];
#pragma unroll
        for (int i = 0; i < 2; ++i)
#pragma unroll
            for (int c = 0; c < 4; ++c) acc[i][c] = (f4){0.f, 0.f, 0.f, 0.f};
#pragma unroll
        for (int j = 0; j < 4; ++j) {
#pragma unroll
            for (int c = 0; c < 4; ++c) {
                sh8 khf = *(const sh8*)&Khi[c * 16 + l15][j * 32 + l4 * 8];
                sh8 klf = *(const sh8*)&Klo[c * 16 + l15][j * 32 + l4 * 8];
#pragma unroll
                for (int i = 0; i < 2; ++i) {
                    acc[i][c] = __builtin_amdgcn_mfma_f32_16x16x32_bf16(qh[i][j], khf, acc[i][c], 0, 0, 0);
                    acc[i][c] = __builtin_amdgcn_mfma_f32_16x16x32_bf16(qh[i][j], klf, acc[i][c], 0, 0, 0);
                    acc[i][c] = __builtin_amdgcn_mfma_f32_16x16x32_bf16(ql[i][j], khf, acc[i][c], 0, 0, 0);
                }
            }
        }

        // ---- p = exp(s) (fixed max = 0), per-lane partial l, Ps in bf16 ----
#pragma unroll
        for (int i = 0; i < 2; ++i) {
#pragma unroll
            for (int c = 0; c < 4; ++c) {
#pragma unroll
                for (int r = 0; r < 4; ++r) {
                    float e_ = __expf(acc[i][c][r]);
                    l_part[i][r] += e_;
                    Ps[wave * 32 + i * 16 + l4 * 4 + r][c * 16 + l15] = bf16_of(e_);
                }
            }
        }
        // NOTE: no barrier — Ps rows are strictly wave-local.

        // ---- PV: per strip O(16x128) += P(16x64) * V(64x128); V reads shared ----
#pragma unroll
        for (int s2 = 0; s2 < 2; ++s2) {
            sh8 pf0 = *(const sh8*)&Ps[wave * 32 + l15][s2 * 32 + l4 * 8];
            sh8 pf1 = *(const sh8*)&Ps[wave * 32 + 16 + l15][s2 * 32 + l4 * 8];
#pragma unroll
            for (int t = 0; t < 8; ++t) {
                sh8 vf = *(const sh8*)&Vt[t * 16 + l15][s2 * 32 + l4 * 8];
                o[0][t] = __builtin_amdgcn_mfma_f32_16x16x32_bf16(pf0, vf, o[0][t], 0, 0, 0);
                o[1][t] = __builtin_amdgcn_mfma_f32_16x16x32_bf16(pf1, vf, o[1][t], 0, 0, 0);
            }
        }
    }

    // ---- epilogue: reduce l across the 16 l15 lanes (once), scale, store ----
#pragma unroll
    for (int i = 0; i < 2; ++i) {
        float inv[4];
#pragma unroll
        for (int r = 0; r < 4; ++r) {
            float l = l_part[i][r];
            l += __shfl_xor(l, 1);
            l += __shfl_xor(l, 2);
            l += __shfl_xor(l, 4);
            l += __shfl_xor(l, 8);
            inv[r] = 1.f / l;
        }
#pragma unroll
        for (int t = 0; t < 8; ++t) {
#pragma unroll
            for (int r = 0; r < 4; ++r) {
                int row = qb * 128 + wave * 32 + i * 16 + l4 * 4 + r;
                Ao[((size_t)b * S_ + row) * (H_ * D_) + h * D_ + t * 16 + l15] = o[i][t][r] * inv[r];
            }
        }
    }
}

// ---------------------------------------------------------------------------
extern "C" void kernel_launch(void* const* d_in, const int* in_sizes, int n_in,
                              void* d_out, int out_size, void* d_ws, size_t ws_size,
                              hipStream_t stream)
{
    const float* hidden  = (const float*)d_in[0];
    const float* cosT    = (const float*)d_in[1];
    const float* sinT    = (const float*)d_in[2];
    const float* w_qkv   = (const float*)d_in[3];
    const float* q_ln    = (const float*)d_in[4];
    const float* k_ln    = (const float*)d_in[5];
    const float* w_dense = (const float*)d_in[6];
    float* out = (float*)d_out;

    float* qkv = (float*)d_ws;
    float* Q   = qkv + (size_t)B_ * S_ * QKVN;
    short* Khi = (short*)(Q + (size_t)B_ * H_ * S_ * D_);
    short* Klo = Khi + (size_t)B_ * HK_ * S_ * D_;
    short* Vt  = Klo + (size_t)B_ * HK_ * S_ * D_;
    float* attn = qkv;   // qkv dead after vtrans; flash never reads it

    // 1) QKV projection (split-bf16 MFMA GEMM)
    gemm_split<<<dim3(QKVN / 128, (B_ * S_) / 128), 256, 0, stream>>>(
        hidden, w_qkv, qkv, B_ * S_, QKVN, HID_);

    // 2) RMSNorm + RoPE; Q fp32, K split-bf16
    norm_rope<<<dim3(20, S_, B_), 128, 0, stream>>>(
        qkv, cosT, sinT, q_ln, k_ln, Q, Khi, Klo);

    // 3) V transpose -> bf16 (B*HK, D, S)
    vtrans<<<dim3(S_ / 64, B_ * HK_), 256, 0, stream>>>(qkv, Vt);

    // 4) MFMA flash attention (Q-tile 128, fixed-max softmax) -> attn (B,S,H*D)
    flash_mfma<<<dim3(S_ / 128, H_, B_), 256, 0, stream>>>(Q, Khi, Klo, Vt, attn);

    // 5) dense projection (split-bf16 MFMA GEMM)
    gemm_split<<<dim3(HID_ / 128, (B_ * S_) / 128), 256, 0, stream>>>(
        attn, w_dense, out, B_ * S_, HID_, H_ * D_);
}

// Round 7
// 438.177 us; speedup vs baseline: 5.4021x; 1.4189x over previous
//
#include <hip/hip_runtime.h>
#include <hip/hip_bf16.h>
#include <math.h>

#define B_   2
#define S_   2048
#define HID_ 2048
#define H_   16
#define HK_  4
#define D_   128
#define NH_  24          // H + 2*HK
#define QKVN 3072        // NH_ * D_
#define R_   64

typedef __attribute__((ext_vector_type(8))) short sh8;       // 8 bf16 MFMA frag
typedef __attribute__((ext_vector_type(8))) _Float16 h8;     // 8 fp16 MFMA frag
typedef __attribute__((ext_vector_type(4))) float f4;        // MFMA accumulator

__device__ __forceinline__ short bf16_of(float x) {
    __hip_bfloat16 h = __float2bfloat16(x);
    return *reinterpret_cast<short*>(&h);
}
__device__ __forceinline__ float f_of_bf16(short s) {
    __hip_bfloat16 h = *reinterpret_cast<__hip_bfloat16*>(&s);
    return __bfloat162float(h);
}

// ---------------------------------------------------------------------------
// fp32 -> fp16 conversion, 8 elems/thread. n8 = n/8.
// ---------------------------------------------------------------------------
__global__ __launch_bounds__(256) void cvt_f16(
    const float* __restrict__ src, _Float16* __restrict__ dst, int n8)
{
    int i = blockIdx.x * 256 + threadIdx.x;
    if (i < n8) {
        float4 a = ((const float4*)src)[i * 2];
        float4 b = ((const float4*)src)[i * 2 + 1];
        h8 h;
        h[0] = (_Float16)a.x; h[1] = (_Float16)a.y;
        h[2] = (_Float16)a.z; h[3] = (_Float16)a.w;
        h[4] = (_Float16)b.x; h[5] = (_Float16)b.y;
        h[6] = (_Float16)b.z; h[7] = (_Float16)b.w;
        ((h8*)dst)[i] = h;
    }
}

// ---------------------------------------------------------------------------
// fp16 MFMA GEMM: C[M][N] = A[M][K] * B[N][K]^T, fp32 accumulate.
// 128x128 block tile, BK=64, 256 threads = 4 waves (2x2), wave tile 64x64.
// Register prefetch of next K-slab during compute. LDS 36.9 KB -> 4 blk/CU.
// ---------------------------------------------------------------------------
template<bool F16OUT>
__global__ __launch_bounds__(256) void gemm_f16(
    const _Float16* __restrict__ A, const _Float16* __restrict__ Bm,
    void* __restrict__ Cv, int M, int N, int K)
{
    __shared__ _Float16 Ast[128][72];   // BK=64 + 8 pad (144B row stride)
    __shared__ _Float16 Bst[128][72];

    const int tid = threadIdx.x;
    const int wave = tid >> 6, lane = tid & 63;
    const int l15 = lane & 15, l4 = lane >> 4;
    const int m0 = blockIdx.y * 128, n0 = blockIdx.x * 128;
    const int wm = (wave >> 1) * 64, wn = (wave & 1) * 64;

    f4 acc[16];
#pragma unroll
    for (int t = 0; t < 16; ++t) acc[t] = (f4){0.f, 0.f, 0.f, 0.f};

    // staging addresses: 4 chunks of 8 f16 per operand per thread
    int srow[4], scol[4];
#pragma unroll
    for (int t = 0; t < 4; ++t) {
        int idx = tid + 256 * t;          // 0..1023
        srow[t] = idx >> 3;               // row 0..127
        scol[t] = (idx & 7) * 8;          // col 0,8,..,56
    }

    // prefetch slab 0
    h8 a_r[4], b_r[4];
#pragma unroll
    for (int t = 0; t < 4; ++t) {
        a_r[t] = *(const h8*)(A  + (size_t)(m0 + srow[t]) * K + scol[t]);
        b_r[t] = *(const h8*)(Bm + (size_t)(n0 + srow[t]) * K + scol[t]);
    }

    for (int k0 = 0; k0 < K; k0 += 64) {
        __syncthreads();   // prev slab's fragment reads done
#pragma unroll
        for (int t = 0; t < 4; ++t) {
            *(h8*)&Ast[srow[t]][scol[t]] = a_r[t];
            *(h8*)&Bst[srow[t]][scol[t]] = b_r[t];
        }
        if (k0 + 64 < K) {
#pragma unroll
            for (int t = 0; t < 4; ++t) {
                a_r[t] = *(const h8*)(A  + (size_t)(m0 + srow[t]) * K + k0 + 64 + scol[t]);
                b_r[t] = *(const h8*)(Bm + (size_t)(n0 + srow[t]) * K + k0 + 64 + scol[t]);
            }
        }
        __syncthreads();

#pragma unroll
        for (int j = 0; j < 2; ++j) {
            h8 ahf[4], bhf[4];
#pragma unroll
            for (int i = 0; i < 4; ++i) {
                ahf[i] = *(const h8*)&Ast[wm + i * 16 + l15][j * 32 + l4 * 8];
                bhf[i] = *(const h8*)&Bst[wn + i * 16 + l15][j * 32 + l4 * 8];
            }
#pragma unroll
            for (int i = 0; i < 4; ++i)
#pragma unroll
                for (int jj = 0; jj < 4; ++jj)
                    acc[i * 4 + jj] = __builtin_amdgcn_mfma_f32_16x16x32_f16(
                        ahf[i], bhf[jj], acc[i * 4 + jj], 0, 0, 0);
        }
    }

#pragma unroll
    for (int i = 0; i < 4; ++i)
#pragma unroll
        for (int jj = 0; jj < 4; ++jj)
#pragma unroll
            for (int r = 0; r < 4; ++r) {
                int row = m0 + wm + i * 16 + l4 * 4 + r;
                int col = n0 + wn + jj * 16 + l15;
                if (F16OUT)
                    ((_Float16*)Cv)[(size_t)row * N + col] = (_Float16)acc[i * 4 + jj][r];
                else
                    ((float*)Cv)[(size_t)row * N + col] = acc[i * 4 + jj][r];
            }
}

// ---------------------------------------------------------------------------
// Fused RMSNorm (q,k heads) + partial RoPE. Input qkv in fp16.
//   h in [0,16)  -> Q fp32 (B,H,S,D)
//   h in [16,20) -> Khi/Klo bf16-split (B,HK,S,D)
// ---------------------------------------------------------------------------
__global__ __launch_bounds__(128) void norm_rope(
    const _Float16* __restrict__ qkv,
    const float* __restrict__ cosT, const float* __restrict__ sinT,
    const float* __restrict__ qw, const float* __restrict__ kw,
    float* __restrict__ Q, short* __restrict__ Khi_g, short* __restrict__ Klo_g)
{
    const int h = blockIdx.x;       // 0..19
    const int s = blockIdx.y;
    const int b = blockIdx.z;
    const int d = threadIdx.x;
    const size_t tok = (size_t)b * S_ + s;

    float x = (float)qkv[(tok * NH_ + h) * D_ + d];
    __shared__ float sh[128];

    sh[d] = x * x;
    __syncthreads();
#pragma unroll
    for (int off = 64; off >= 1; off >>= 1) {
        if (d < off) sh[d] += sh[d + off];
        __syncthreads();
    }
    float var = sh[0] * (1.f / 128.f);
    float scale = rsqrtf(var + 1e-6f);
    const float* w = (h < 16) ? qw : kw;
    float y = x * scale * w[d];
    __syncthreads();
    sh[d] = y;
    __syncthreads();
    if (d < R_) {
        float c  = cosT[tok * R_ + d];
        float sn = sinT[tok * R_ + d];
        float other = (d < 32) ? -sh[d + 32] : sh[d - 32];
        y = y * c + other * sn;
    }

    if (h < 16) {
        Q[(((size_t)b * H_ + h) * S_ + s) * D_ + d] = y;
    } else {
        size_t idx = (((size_t)b * HK_ + (h - 16)) * S_ + s) * D_ + d;
        short hi = bf16_of(y);
        Khi_g[idx] = hi;
        Klo_g[idx] = bf16_of(y - f_of_bf16(hi));
    }
}

// ---------------------------------------------------------------------------
// V transpose: reads V heads out of fp16 qkv, writes bf16 Vt (B*HK, D, S).
// ---------------------------------------------------------------------------
__global__ __launch_bounds__(256) void vtrans(
    const _Float16* __restrict__ qkv, short* __restrict__ Vt_g)
{
    __shared__ float Ts[64][132];
    const int tid = threadIdx.x;
    const int sb = blockIdx.x;
    const int bh = blockIdx.y;
    const int b = bh >> 2, kh = bh & 3;

#pragma unroll
    for (int t = 0; t < 4; ++t) {
        int e = (tid + 256 * t) * 8;
        int s = e >> 7, d = e & 127;
        const _Float16* p = qkv + (((size_t)(b * S_ + sb * 64 + s)) * NH_ + 20 + kh) * D_ + d;
        h8 v = *(const h8*)p;
#pragma unroll
        for (int u = 0; u < 8; ++u) Ts[s][d + u] = (float)v[u];
    }
    __syncthreads();

#pragma unroll
    for (int tt = 0; tt < 2; ++tt) {
        int dr = (tid >> 2) + 64 * tt;
        int sc = (tid & 3) * 16;
        short tmp[16];
#pragma unroll
        for (int i = 0; i < 16; ++i) tmp[i] = bf16_of(Ts[sc + i][dr]);
        short* outp = Vt_g + ((size_t)bh * D_ + dr) * S_ + sb * 64 + sc;
        *(sh8*)outp       = *(sh8*)&tmp[0];
        *(sh8*)(outp + 8) = *(sh8*)&tmp[8];
    }
}

// ---------------------------------------------------------------------------
// MFMA flash attention, fixed-max softmax (scores bounded by RMS norm:
// |s| <= sqrt(128)), Q-tile 128, KV-tile 64, register prefetch of K/V.
// Output attn written as fp16 (feeds the fp16 dense GEMM).
// ---------------------------------------------------------------------------
__global__ __launch_bounds__(256, 2) void flash_mfma(
    const float* __restrict__ Q, const short* __restrict__ Khi_g,
    const short* __restrict__ Klo_g, const short* __restrict__ Vt_g,
    _Float16* __restrict__ Ao)
{
    __shared__ short Khi[64][136];   // pad 8: row stride 272B
    __shared__ short Klo[64][136];
    __shared__ short Vt[128][72];    // V^T: [d][kv]
    __shared__ short Ps[128][72];    // P in A-operand feed layout

    const int tid = threadIdx.x;
    const int wave = tid >> 6, lane = tid & 63;
    const int l15 = lane & 15, l4 = lane >> 4;
    const int qb = blockIdx.x, h = blockIdx.y, b = blockIdx.z;
    const int kh = h >> 2;

    // ---- Q fragments (hi/lo split) for both 16-row strips ----
    const float qscale = 0.08838834764831845f;  // 1/sqrt(128)
    sh8 qh[2][4], ql[2][4];
#pragma unroll
    for (int i = 0; i < 2; ++i) {
        const float* qrow = Q + (((size_t)b * H_ + h) * S_ + qb * 128 + wave * 32 + i * 16 + l15) * D_;
#pragma unroll
        for (int j = 0; j < 4; ++j) {
            int d0 = j * 32 + l4 * 8;
#pragma unroll
            for (int jj = 0; jj < 8; ++jj) {
                float x = qrow[d0 + jj] * qscale;
                short hi = bf16_of(x);
                qh[i][j][jj] = hi;
                ql[i][j][jj] = bf16_of(x - f_of_bf16(hi));
            }
        }
    }

    f4 o[2][8];
#pragma unroll
    for (int i = 0; i < 2; ++i)
#pragma unroll
        for (int t = 0; t < 8; ++t) o[i][t] = (f4){0.f, 0.f, 0.f, 0.f};
    float l_part[2][4] = {{0.f, 0.f, 0.f, 0.f}, {0.f, 0.f, 0.f, 0.f}};

    const size_t kvoff = ((size_t)b * HK_ + kh) * S_ * D_;
    const short* khg = Khi_g + kvoff;
    const short* klg = Klo_g + kvoff;
    const short* vtg = Vt_g + kvoff;

    int srow[4], scol[4], vrow[4], vcol[4];
#pragma unroll
    for (int t = 0; t < 4; ++t) {
        int e = (tid + 256 * t) * 8;
        srow[t] = e >> 7; scol[t] = e & 127;
        vrow[t] = e >> 6; vcol[t] = e & 63;
    }

    sh8 kh_r[4], kl_r[4], vt_r[4];
#pragma unroll
    for (int t = 0; t < 4; ++t) {
        kh_r[t] = *(const sh8*)(khg + (size_t)srow[t] * D_ + scol[t]);
        kl_r[t] = *(const sh8*)(klg + (size_t)srow[t] * D_ + scol[t]);
        vt_r[t] = *(const sh8*)(vtg + (size_t)vrow[t] * S_ + vcol[t]);
    }

    for (int kb = 0; kb < S_ / 64; ++kb) {
        __syncthreads();
#pragma unroll
        for (int t = 0; t < 4; ++t) {
            *(sh8*)&Khi[srow[t]][scol[t]] = kh_r[t];
            *(sh8*)&Klo[srow[t]][scol[t]] = kl_r[t];
            *(sh8*)&Vt[vrow[t]][vcol[t]]  = vt_r[t];
        }
        if (kb + 1 < S_ / 64) {
            int off = (kb + 1) * 64;
#pragma unroll
            for (int t = 0; t < 4; ++t) {
                kh_r[t] = *(const sh8*)(khg + (size_t)(off + srow[t]) * D_ + scol[t]);
                kl_r[t] = *(const sh8*)(klg + (size_t)(off + srow[t]) * D_ + scol[t]);
                vt_r[t] = *(const sh8*)(vtg + (size_t)vrow[t] * S_ + off + vcol[t]);
            }
        }
        __syncthreads();

        f4 acc[2][4];
#pragma unroll
        for (int i = 0; i < 2; ++i)
#pragma unroll
            for (int c = 0; c < 4; ++c) acc[i][c] = (f4){0.f, 0.f, 0.f, 0.f};
#pragma unroll
        for (int j = 0; j < 4; ++j) {
#pragma unroll
            for (int c = 0; c < 4; ++c) {
                sh8 khf = *(const sh8*)&Khi[c * 16 + l15][j * 32 + l4 * 8];
                sh8 klf = *(const sh8*)&Klo[c * 16 + l15][j * 32 + l4 * 8];
#pragma unroll
                for (int i = 0; i < 2; ++i) {
                    acc[i][c] = __builtin_amdgcn_mfma_f32_16x16x32_bf16(qh[i][j], khf, acc[i][c], 0, 0, 0);
                    acc[i][c] = __builtin_amdgcn_mfma_f32_16x16x32_bf16(qh[i][j], klf, acc[i][c], 0, 0, 0);
                    acc[i][c] = __builtin_amdgcn_mfma_f32_16x16x32_bf16(ql[i][j], khf, acc[i][c], 0, 0, 0);
                }
            }
        }

#pragma unroll
        for (int i = 0; i < 2; ++i) {
#pragma unroll
            for (int c = 0; c < 4; ++c) {
#pragma unroll
                for (int r = 0; r < 4; ++r) {
                    float e_ = __expf(acc[i][c][r]);
                    l_part[i][r] += e_;
                    Ps[wave * 32 + i * 16 + l4 * 4 + r][c * 16 + l15] = bf16_of(e_);
                }
            }
        }
        // no barrier — Ps rows are strictly wave-local

#pragma unroll
        for (int s2 = 0; s2 < 2; ++s2) {
            sh8 pf0 = *(const sh8*)&Ps[wave * 32 + l15][s2 * 32 + l4 * 8];
            sh8 pf1 = *(const sh8*)&Ps[wave * 32 + 16 + l15][s2 * 32 + l4 * 8];
#pragma unroll
            for (int t = 0; t < 8; ++t) {
                sh8 vf = *(const sh8*)&Vt[t * 16 + l15][s2 * 32 + l4 * 8];
                o[0][t] = __builtin_amdgcn_mfma_f32_16x16x32_bf16(pf0, vf, o[0][t], 0, 0, 0);
                o[1][t] = __builtin_amdgcn_mfma_f32_16x16x32_bf16(pf1, vf, o[1][t], 0, 0, 0);
            }
        }
    }

#pragma unroll
    for (int i = 0; i < 2; ++i) {
        float inv[4];
#pragma unroll
        for (int r = 0; r < 4; ++r) {
            float l = l_part[i][r];
            l += __shfl_xor(l, 1);
            l += __shfl_xor(l, 2);
            l += __shfl_xor(l, 4);
            l += __shfl_xor(l, 8);
            inv[r] = 1.f / l;
        }
#pragma unroll
        for (int t = 0; t < 8; ++t) {
#pragma unroll
            for (int r = 0; r < 4; ++r) {
                int row = qb * 128 + wave * 32 + i * 16 + l4 * 4 + r;
                Ao[((size_t)b * S_ + row) * (H_ * D_) + h * D_ + t * 16 + l15] =
                    (_Float16)(o[i][t][r] * inv[r]);
            }
        }
    }
}

// ---------------------------------------------------------------------------
extern "C" void kernel_launch(void* const* d_in, const int* in_sizes, int n_in,
                              void* d_out, int out_size, void* d_ws, size_t ws_size,
                              hipStream_t stream)
{
    const float* hidden  = (const float*)d_in[0];
    const float* cosT    = (const float*)d_in[1];
    const float* sinT    = (const float*)d_in[2];
    const float* w_qkv   = (const float*)d_in[3];
    const float* q_ln    = (const float*)d_in[4];
    const float* k_ln    = (const float*)d_in[5];
    const float* w_dense = (const float*)d_in[6];
    float* out = (float*)d_out;

    // workspace layout (bytes):
    //   qkv16    : B*S*3072 f16   = 25,165,824   [attn16 aliases first 16.8 MB]
    //   Q        : B*H*S*D fp32   = 33,554,432   [hidden16 aliases first 16.8 MB]
    //   Khi/Klo/Vt: 3 x 4,194,304 = 12,582,912   [wqkv16 aliases all 12.6 MB]
    //   wdense16 : 2048*2048 f16  =  8,388,608
    // total 79.7 MB
    char* w = (char*)d_ws;
    _Float16* qkv16 = (_Float16*)w;
    float*    Q     = (float*)(w + 25165824);
    short*    Khi   = (short*)(w + 25165824 + 33554432);
    short*    Klo   = Khi + 2097152;
    short*    Vt    = Klo + 2097152;
    _Float16* wdense16 = (_Float16*)(w + 25165824 + 33554432 + 12582912);
    _Float16* hidden16 = (_Float16*)Q;      // dead before norm_rope writes Q
    _Float16* wqkv16   = (_Float16*)Khi;    // dead before norm_rope writes K
    _Float16* attn16   = qkv16;             // qkv16 dead after vtrans

    // 0) fp32 -> fp16 operand conversions
    cvt_f16<<<4096, 256, 0, stream>>>(hidden, hidden16, 1048576);
    cvt_f16<<<3072, 256, 0, stream>>>(w_qkv, wqkv16, 786432);
    cvt_f16<<<2048, 256, 0, stream>>>(w_dense, wdense16, 524288);

    // 1) QKV projection (fp16 MFMA GEMM, f16 out)
    gemm_f16<true><<<dim3(QKVN / 128, (B_ * S_) / 128), 256, 0, stream>>>(
        hidden16, wqkv16, qkv16, B_ * S_, QKVN, HID_);

    // 2) RMSNorm + RoPE; Q fp32, K split-bf16
    norm_rope<<<dim3(20, S_, B_), 128, 0, stream>>>(
        qkv16, cosT, sinT, q_ln, k_ln, Q, Khi, Klo);

    // 3) V transpose -> bf16 (B*HK, D, S)
    vtrans<<<dim3(S_ / 64, B_ * HK_), 256, 0, stream>>>(qkv16, Vt);

    // 4) MFMA flash attention -> attn16 (B,S,H*D) fp16
    flash_mfma<<<dim3(S_ / 128, H_, B_), 256, 0, stream>>>(Q, Khi, Klo, Vt, attn16);

    // 5) dense projection (fp16 MFMA GEMM, fp32 out)
    gemm_f16<false><<<dim3(HID_ / 128, (B_ * S_) / 128), 256, 0, stream>>>(
        attn16, wdense16, out, B_ * S_, HID_, H_ * D_);
}